// Round 8
// baseline (614.675 us; speedup 1.0000x reference)
//
#include <hip/hip_runtime.h>

#define BN_EPS 1e-5f

typedef __attribute__((ext_vector_type(8))) short bf16x8;
typedef __attribute__((ext_vector_type(4))) float f32x4;

__device__ __forceinline__ unsigned short f2bf(float f) {
    unsigned u = __float_as_uint(f);
    return (unsigned short)((u + 0x7fffu + ((u >> 16) & 1u)) >> 16);   // RNE
}

// ---------------------------------------------------------------------------
// Weight transform: w[co][ci][3][3] fp32 -> wt[tap][co_pad][ci] bf16 (zero pad)
// z: 0..2 fpn0/1/2 (co 64->64), 3..4 enc0/1 (co 100->112). grid (252, 5)
// ---------------------------------------------------------------------------
__global__ __launch_bounds__(256)
void wt_transform(const float* __restrict__ w0, const float* __restrict__ w1,
                  const float* __restrict__ w2, const float* __restrict__ w3,
                  const float* __restrict__ w4, unsigned short* __restrict__ dst)
{
    int z = blockIdx.y;
    int i = blockIdx.x * 256 + threadIdx.x;
    const float* src; unsigned short* d; int C_out, COP;
    if (z < 3) {
        COP = 64; C_out = 64;
        src = (z == 0) ? w0 : (z == 1 ? w1 : w2);
        d = dst + z * 36864;
        if (i >= 36864) return;
    } else {
        COP = 112; C_out = 100;
        src = (z == 3) ? w3 : w4;
        d = dst + 110592 + (z - 3) * 64512;
        if (i >= 64512) return;
    }
    int tap = i / (COP * 64);
    int rem = i - tap * (COP * 64);
    int co = rem >> 6, ci = rem & 63;
    float v = (co < C_out) ? src[((size_t)co * 64 + ci) * 9 + tap] : 0.f;
    d[i] = f2bf(v);
}

// ---------------------------------------------------------------------------
// conv3x3 via bf16 MFMA (16x16x32), pad=1, C_in=64, fp32 accumulate.
// (R5 version — known good: absmax 0.031 < 0.128)
// grid: (ceil(W/16), ceil(H/16), B), block 256
// ---------------------------------------------------------------------------
template<int COP, int MODE>
__global__ __launch_bounds__(256, 4)
void conv3x3_mfma(const float* __restrict__ x, const unsigned short* __restrict__ wt,
                  const float* __restrict__ p0, const float* __restrict__ p1,
                  const float* __restrict__ p2, const float* __restrict__ p3,
                  float* __restrict__ out, int H, int W, int C_out)
{
    constexpr int NP = 324;                      // 18*18 halo pixels
    __shared__ unsigned short xs[8 * NP * 8];    // [cg][p][8ci] bf16, 41472 B

    int tid  = threadIdx.x;
    int lane = tid & 63, wid = tid >> 6;
    int lrow = lane >> 4, lcol = lane & 15;      // lrow = quad
    int x0 = blockIdx.x * 16, y0 = blockIdx.y * 16;
    int b  = blockIdx.z;
    int HWp = H * W;
    const float* xb = x + (size_t)b * 64 * HWp;

    unsigned int* wsl = (unsigned int*)xs;
    for (int p = tid; p < NP; p += 256) {
        int py = p / 18, px = p - py * 18;
        int gy = y0 + py - 1, gx = x0 + px - 1;
        bool ok = (gy >= 0) && (gy < H) && (gx >= 0) && (gx < W);
        const float* gp = xb + (size_t)gy * W + gx;
#pragma unroll 4
        for (int cp = 0; cp < 32; ++cp) {        // ci pair
            float v0 = 0.f, v1 = 0.f;
            if (ok) {
                v0 = gp[(size_t)(2 * cp) * HWp];
                v1 = gp[(size_t)(2 * cp + 1) * HWp];
            }
            unsigned pk = ((unsigned)f2bf(v1) << 16) | (unsigned)f2bf(v0);
            wsl[((cp >> 2) * NP + p) * 4 + (cp & 3)] = pk;
        }
    }
    __syncthreads();

    bool colok = (x0 + lcol) < W;

    for (int ct = 0; ct < COP / 16; ++ct) {
        int co0 = ct * 16;

        bf16x8 a[9][2];
        const unsigned short* wl = wt + ((size_t)co0 + lcol) * 64 + lrow * 8;
#pragma unroll
        for (int t = 0; t < 9; ++t)
#pragma unroll
            for (int kb = 0; kb < 2; ++kb)
                a[t][kb] = *(const bf16x8*)(wl + (size_t)t * COP * 64 + kb * 32);

        float sc[4], sh[4];
#pragma unroll
        for (int rg = 0; rg < 4; ++rg) {
            int co = co0 + lrow * 4 + rg;
            int cc = (co < C_out) ? co : 0;
            if (MODE == 0) { sc[rg] = 1.f; sh[rg] = p0[cc]; }
            else {
                float inv = p0[cc] * rsqrtf(p3[cc] + BN_EPS);
                sc[rg] = inv; sh[rg] = p1[cc] - p2[cc] * inv;
            }
        }

#pragma unroll
        for (int rr = 0; rr < 2; ++rr) {
            int r0 = wid + rr * 8;
            f32x4 acc0 = {0.f, 0.f, 0.f, 0.f};
            f32x4 acc1 = {0.f, 0.f, 0.f, 0.f};
#pragma unroll
            for (int t = 0; t < 9; ++t) {
                int dy = t / 3, dx = t - dy * 3;
#pragma unroll
                for (int kb = 0; kb < 2; ++kb) {
                    int g0 = (kb * 4 + lrow) * NP + (r0 + dy) * 18 + lcol + dx;
                    bf16x8 b0 = *(const bf16x8*)(xs + (size_t)g0 * 8);
                    acc0 = __builtin_amdgcn_mfma_f32_16x16x32_bf16(a[t][kb], b0, acc0, 0, 0, 0);
                    bf16x8 b1 = *(const bf16x8*)(xs + ((size_t)g0 + 4 * 18) * 8);
                    acc1 = __builtin_amdgcn_mfma_f32_16x16x32_bf16(a[t][kb], b1, acc1, 0, 0, 0);
                }
            }
            int yA = y0 + r0, yB = y0 + r0 + 4;
#pragma unroll
            for (int rg = 0; rg < 4; ++rg) {
                int co = co0 + lrow * 4 + rg;
                if (colok && co < C_out) {
                    float* oc = out + (((size_t)b * C_out + co) * H) * W + x0 + lcol;
                    if (yA < H) oc[(size_t)yA * W] = acc0[rg] * sc[rg] + sh[rg];
                    if (yB < H) oc[(size_t)yB * W] = acc1[rg] * sc[rg] + sh[rg];
                }
            }
        }
    }
}

// ---------------------------------------------------------------------------
// conv1x1 v3: register-tiled GEMM. Block = ALL 64 co x PXT pixels, so the
// input is fetched ONCE (v2's blockIdx.y co-split re-read x 8x: lat0 FETCH
// 123MB vs 31MB input, 70us). Per-thread 8co x PQ px micro-tile in regs;
// K staged in 32-ci chunks (x: coalesced float4 -> LDS; w: 32x64 -> LDS).
// LDS reads: x strided-32 (2-way alias = free), w broadcast.
// MODE 0: + bias (p0)   MODE 1: BN(g,bt,m,v) + ReLU
// grid: (ceil(HW/PXT), B), block 256.  Requires HW % 4 == 0.
// ---------------------------------------------------------------------------
template<int C_IN, int PXT, int MODE>
__global__ __launch_bounds__(256, 2)
void conv1x1_gemm(const float* __restrict__ x, const float* __restrict__ w,
                  const float* __restrict__ p0, const float* __restrict__ p1,
                  const float* __restrict__ p2, const float* __restrict__ p3,
                  float* __restrict__ out, int HW)
{
    constexpr int KC = 32;
    constexpr int PQ = PXT / 32;               // px per thread
    __shared__ float xs[KC][PXT];
    __shared__ float ws[KC][64];

    int tid = threadIdx.x;
    int tp = tid & 31, tc = tid >> 5;          // px lane, co octet
    int px0 = blockIdx.x * PXT;
    int b   = blockIdx.y;
    const float* xb = x + (size_t)b * C_IN * HW;

    float acc[8][PQ];
#pragma unroll
    for (int j = 0; j < 8; ++j)
#pragma unroll
        for (int q = 0; q < PQ; ++q) acc[j][q] = 0.f;

    for (int cc = 0; cc < C_IN; cc += KC) {
        if (cc) __syncthreads();
        // stage x chunk: KC x PXT floats as float4
#pragma unroll
        for (int t = 0; t < KC * PXT / 4 / 256; ++t) {
            int i = tid + t * 256;
            int k = i / (PXT / 4);
            int u = i - k * (PXT / 4);
            int p = px0 + 4 * u;
            float4 v = make_float4(0.f, 0.f, 0.f, 0.f);
            if (p < HW) v = *(const float4*)(xb + (size_t)(cc + k) * HW + p);
            *(float4*)&xs[k][4 * u] = v;
        }
        // stage w chunk: KC x 64 (transposed)
#pragma unroll
        for (int t = 0; t < 8; ++t) {
            int i = tid + t * 256;
            int k = i >> 6, co = i & 63;
            ws[k][co] = w[(size_t)co * C_IN + cc + k];
        }
        __syncthreads();

#pragma unroll
        for (int k = 0; k < KC; ++k) {
            float xv[PQ];
#pragma unroll
            for (int q = 0; q < PQ; ++q) xv[q] = xs[k][tp + 32 * q];
            float4 wa = *(const float4*)&ws[k][tc * 8];
            float4 wb = *(const float4*)&ws[k][tc * 8 + 4];
            float wv[8] = {wa.x, wa.y, wa.z, wa.w, wb.x, wb.y, wb.z, wb.w};
#pragma unroll
            for (int j = 0; j < 8; ++j)
#pragma unroll
                for (int q = 0; q < PQ; ++q)
                    acc[j][q] = fmaf(wv[j], xv[q], acc[j][q]);
        }
    }

#pragma unroll
    for (int j = 0; j < 8; ++j) {
        int co = tc * 8 + j;
        float scale, shift;
        if (MODE == 0) {
            scale = 1.f; shift = p0[co];
        } else {
            float inv = p0[co] * rsqrtf(p3[co] + BN_EPS);
            scale = inv; shift = p1[co] - p2[co] * inv;
        }
        float* op = out + ((size_t)(b * 64 + co)) * HW;
#pragma unroll
        for (int q = 0; q < PQ; ++q) {
            int p = px0 + tp + 32 * q;
            if (p < HW) {
                float r = acc[j][q] * scale + shift;
                if (MODE == 1) r = fmaxf(r, 0.f);
                op[p] = r;
            }
        }
    }
}

// ---------------------------------------------------------------------------
// CARAFE v3 (R6 version — known good: LDS-staged src patch, softmax once)
// grid: (2w/16, 2h/16, B), block 256
// ---------------------------------------------------------------------------
__global__ __launch_bounds__(256, 4)
void carafe_kernel(const float* __restrict__ src, const float* __restrict__ logits,
                   float* __restrict__ dst, int h, int w)
{
    constexpr int SW = 12, NPX = 144, CS = 68;
    __shared__ float ls[NPX * CS];

    int tid = threadIdx.x;
    int x0 = blockIdx.x * 16, y0 = blockIdx.y * 16;
    int b = blockIdx.z;
    int H = 2 * h, W = 2 * w;
    int xs0 = (x0 >> 1) - 2, ys0 = (y0 >> 1) - 2;
    size_t hw = (size_t)h * w;
    const float* sb = src + (size_t)b * 64 * hw;

    for (int i = tid; i < NPX * 64; i += 256) {
        int c = i / NPX, p = i - c * NPX;
        int yy = p / SW, xx = p - yy * SW;
        int sy = ys0 + yy, sx = xs0 + xx;
        float v = 0.f;
        if (sy >= 0 && sy < h && sx >= 0 && sx < w)
            v = sb[(size_t)c * hw + (size_t)sy * w + sx];
        ls[p * CS + c] = v;
    }
    __syncthreads();

    int lx = tid & 15, ty = tid >> 4;
    int x = x0 + lx, y = y0 + ty;
    int xw = x >> 1, yh = y >> 1;
    int par = (y & 1) * 2 + (x & 1);

    const float* lp = logits + ((size_t)(b * 100 + par) * h + yh) * w + xw;
    float l[25];
    float mx = -1e30f;
#pragma unroll
    for (int k = 0; k < 25; ++k) {
        l[k] = lp[(size_t)(4 * k) * hw];
        mx = fmaxf(mx, l[k]);
    }
    float s = 0.f;
#pragma unroll
    for (int k = 0; k < 25; ++k) {
        l[k] = __expf(l[k] - mx);
        s += l[k];
    }
    float invs = 1.f / s;
#pragma unroll
    for (int k = 0; k < 25; ++k) l[k] *= invs;

    int pb = (yh - ys0 - 2) * SW + (xw - xs0 - 2);

#pragma unroll 1
    for (int cg = 0; cg < 4; ++cg) {
        float acc[16];
#pragma unroll
        for (int c = 0; c < 16; ++c) acc[c] = 0.f;
#pragma unroll
        for (int k = 0; k < 25; ++k) {
            int ti = k / 5, tj = k - ti * 5;
            const float* q = &ls[(pb + ti * SW + tj) * CS + cg * 16];
            float wk = l[k];
#pragma unroll
            for (int c = 0; c < 16; ++c)
                acc[c] = fmaf(wk, q[c], acc[c]);
        }
        float* dp = dst + (((size_t)(b * 64 + cg * 16)) * H + y) * W + x;
#pragma unroll
        for (int c = 0; c < 16; ++c)
            dp[(size_t)c * H * W] += acc[c];
    }
}

// ---------------------------------------------------------------------------
extern "C" void kernel_launch(void* const* d_in, const int* in_sizes, int n_in,
                              void* d_out, int out_size, void* d_ws, size_t ws_size,
                              hipStream_t stream)
{
    const float* x0      = (const float*)d_in[0];
    const float* lat0_w  = (const float*)d_in[1];
    const float* lat0_b  = (const float*)d_in[2];
    const float* fpn0_w  = (const float*)d_in[3];
    const float* fpn0_b  = (const float*)d_in[4];
    const float* x1      = (const float*)d_in[5];
    const float* lat1_w  = (const float*)d_in[6];
    const float* lat1_b  = (const float*)d_in[7];
    const float* fpn1_w  = (const float*)d_in[8];
    const float* fpn1_b  = (const float*)d_in[9];
    const float* x2      = (const float*)d_in[10];
    const float* lat2_w  = (const float*)d_in[11];
    const float* lat2_b  = (const float*)d_in[12];
    const float* fpn2_w  = (const float*)d_in[13];
    const float* fpn2_b  = (const float*)d_in[14];
    const float* u0_comp_w = (const float*)d_in[15];
    const float* u0_enc_w  = (const float*)d_in[16];
    const float* u0_comp_g  = (const float*)d_in[17];
    const float* u0_comp_bt = (const float*)d_in[18];
    const float* u0_comp_m  = (const float*)d_in[19];
    const float* u0_comp_v  = (const float*)d_in[20];
    const float* u0_enc_g   = (const float*)d_in[21];
    const float* u0_enc_bt  = (const float*)d_in[22];
    const float* u0_enc_m   = (const float*)d_in[23];
    const float* u0_enc_v   = (const float*)d_in[24];
    const float* u1_comp_w = (const float*)d_in[25];
    const float* u1_enc_w  = (const float*)d_in[26];
    const float* u1_comp_g  = (const float*)d_in[27];
    const float* u1_comp_bt = (const float*)d_in[28];
    const float* u1_comp_m  = (const float*)d_in[29];
    const float* u1_comp_v  = (const float*)d_in[30];
    const float* u1_enc_g   = (const float*)d_in[31];
    const float* u1_enc_bt  = (const float*)d_in[32];
    const float* u1_enc_m   = (const float*)d_in[33];
    const float* u1_enc_v   = (const float*)d_in[34];

    float* out = (float*)d_out;
    const size_t OUT0 = 4ull * 64 * 96 * 160;   // 3,932,160
    const size_t OUT1 = 4ull * 64 * 48 * 80;    //   983,040
    const size_t OUT2 = 4ull * 64 * 24 * 40;    //   245,760
    float* out0 = out;
    float* out1 = out + OUT0;
    float* out2 = out + OUT0 + OUT1;

    float* lat0 = (float*)d_ws;
    float* lat1 = lat0 + OUT0;
    float* lat2 = lat1 + OUT1;
    unsigned short* wtb = (unsigned short*)(lat2 + OUT2);
    unsigned short* wt_fpn0 = wtb;
    unsigned short* wt_fpn1 = wtb + 36864;
    unsigned short* wt_fpn2 = wtb + 73728;
    unsigned short* wt_enc0 = wtb + 110592;
    unsigned short* wt_enc1 = wtb + 175104;
    // comp/enc scratch lives in the out0 region (overwritten last by fpn0 conv)
    float* comp = out0;
    float* enc  = out0 + OUT1;

    dim3 blk(256);

    // 0) weight transform (all 5 conv3x3 weight sets -> bf16 [tap][co][ci])
    wt_transform<<<dim3(252, 5), blk, 0, stream>>>(
        fpn0_w, fpn1_w, fpn2_w, u0_enc_w, u1_enc_w, wtb);

    // 1) lateral 1x1 convs + bias (GEMM: input read once)
    conv1x1_gemm<128, 256, 0><<<dim3(60, 4), blk, 0, stream>>>(
        x0, lat0_w, lat0_b, nullptr, nullptr, nullptr, lat0, 96 * 160);
    conv1x1_gemm<256, 128, 0><<<dim3(30, 4), blk, 0, stream>>>(
        x1, lat1_w, lat1_b, nullptr, nullptr, nullptr, lat1, 48 * 80);
    conv1x1_gemm<512, 64, 0><<<dim3(15, 4), blk, 0, stream>>>(
        x2, lat2_w, lat2_b, nullptr, nullptr, nullptr, lat2, 24 * 40);

    // 2) CARAFE u1: lat1 += carafe(lat2)
    conv1x1_gemm<64, 64, 1><<<dim3(15, 4), blk, 0, stream>>>(
        lat2, u1_comp_w, u1_comp_g, u1_comp_bt, u1_comp_m, u1_comp_v, comp, 24 * 40);
    conv3x3_mfma<112, 1><<<dim3(3, 2, 4), blk, 0, stream>>>(
        comp, wt_enc1, u1_enc_g, u1_enc_bt, u1_enc_m, u1_enc_v, enc, 24, 40, 100);
    carafe_kernel<<<dim3(5, 3, 4), blk, 0, stream>>>(lat2, enc, lat1, 24, 40);

    // 3) CARAFE u0: lat0 += carafe(lat1)
    conv1x1_gemm<64, 128, 1><<<dim3(30, 4), blk, 0, stream>>>(
        lat1, u0_comp_w, u0_comp_g, u0_comp_bt, u0_comp_m, u0_comp_v, comp, 48 * 80);
    conv3x3_mfma<112, 1><<<dim3(5, 3, 4), blk, 0, stream>>>(
        comp, wt_enc0, u0_enc_g, u0_enc_bt, u0_enc_m, u0_enc_v, enc, 48, 80, 100);
    carafe_kernel<<<dim3(10, 6, 4), blk, 0, stream>>>(lat1, enc, lat0, 48, 80);

    // 4) output 3x3 convs + bias  (fpn0 LAST — its region held comp/enc scratch)
    conv3x3_mfma<64, 0><<<dim3(5, 3, 4), blk, 0, stream>>>(
        lat1, wt_fpn1, fpn1_b, nullptr, nullptr, nullptr, out1, 48, 80, 64);
    conv3x3_mfma<64, 0><<<dim3(3, 2, 4), blk, 0, stream>>>(
        lat2, wt_fpn2, fpn2_b, nullptr, nullptr, nullptr, out2, 24, 40, 64);
    conv3x3_mfma<64, 0><<<dim3(10, 6, 4), blk, 0, stream>>>(
        lat0, wt_fpn0, fpn0_b, nullptr, nullptr, nullptr, out0, 96, 160, 64);
}

// Round 9
// 551.970 us; speedup vs baseline: 1.1136x; 1.1136x over previous
//
#include <hip/hip_runtime.h>

#define BN_EPS 1e-5f

typedef __attribute__((ext_vector_type(8))) short bf16x8;
typedef __attribute__((ext_vector_type(4))) float f32x4;

__device__ __forceinline__ unsigned short f2bf(float f) {
    unsigned u = __float_as_uint(f);
    return (unsigned short)((u + 0x7fffu + ((u >> 16) & 1u)) >> 16);   // RNE
}

// ---------------------------------------------------------------------------
// Weight transform: w[co][ci][3][3] fp32 -> wt[tap][co_pad][ci] bf16 (zero pad)
// z: 0..2 fpn0/1/2 (co 64->64), 3..4 enc0/1 (co 100->112). grid (252, 5)
// ---------------------------------------------------------------------------
__global__ __launch_bounds__(256)
void wt_transform(const float* __restrict__ w0, const float* __restrict__ w1,
                  const float* __restrict__ w2, const float* __restrict__ w3,
                  const float* __restrict__ w4, unsigned short* __restrict__ dst)
{
    int z = blockIdx.y;
    int i = blockIdx.x * 256 + threadIdx.x;
    const float* src; unsigned short* d; int C_out, COP;
    if (z < 3) {
        COP = 64; C_out = 64;
        src = (z == 0) ? w0 : (z == 1 ? w1 : w2);
        d = dst + z * 36864;
        if (i >= 36864) return;
    } else {
        COP = 112; C_out = 100;
        src = (z == 3) ? w3 : w4;
        d = dst + 110592 + (z - 3) * 64512;
        if (i >= 64512) return;
    }
    int tap = i / (COP * 64);
    int rem = i - tap * (COP * 64);
    int co = rem >> 6, ci = rem & 63;
    float v = (co < C_out) ? src[((size_t)co * 64 + ci) * 9 + tap] : 0.f;
    d[i] = f2bf(v);
}

// ---------------------------------------------------------------------------
// 1x1 weight transpose: w[co][ci] -> wT[ci][co] fp32 (coalesced GEMM staging).
// z: 0 lat0(128ci) 1 lat1(256) 2 lat2(512) 3 comp0(64) 4 comp1(64). grid(128,5)
// ---------------------------------------------------------------------------
__global__ __launch_bounds__(256)
void w1_transpose(const float* __restrict__ w0, const float* __restrict__ w1,
                  const float* __restrict__ w2, const float* __restrict__ w3,
                  const float* __restrict__ w4, float* __restrict__ dst)
{
    int z = blockIdx.y;
    int i = blockIdx.x * 256 + threadIdx.x;
    int CIN; const float* s; int off;
    if (z == 0)      { CIN = 128; s = w0; off = 0; }
    else if (z == 1) { CIN = 256; s = w1; off = 8192; }
    else if (z == 2) { CIN = 512; s = w2; off = 24576; }
    else if (z == 3) { CIN = 64;  s = w3; off = 57344; }
    else             { CIN = 64;  s = w4; off = 61440; }
    if (i >= CIN * 64) return;
    int ci = i >> 6, co = i & 63;
    dst[off + ci * 64 + co] = s[(size_t)co * CIN + ci];
}

// ---------------------------------------------------------------------------
// conv3x3 via bf16 MFMA (16x16x32), pad=1, C_in=64, fp32 accumulate.
// (R5 version — known good)
// grid: (ceil(W/16), ceil(H/16), B), block 256
// ---------------------------------------------------------------------------
template<int COP, int MODE>
__global__ __launch_bounds__(256, 4)
void conv3x3_mfma(const float* __restrict__ x, const unsigned short* __restrict__ wt,
                  const float* __restrict__ p0, const float* __restrict__ p1,
                  const float* __restrict__ p2, const float* __restrict__ p3,
                  float* __restrict__ out, int H, int W, int C_out)
{
    constexpr int NP = 324;
    __shared__ unsigned short xs[8 * NP * 8];

    int tid  = threadIdx.x;
    int lane = tid & 63, wid = tid >> 6;
    int lrow = lane >> 4, lcol = lane & 15;
    int x0 = blockIdx.x * 16, y0 = blockIdx.y * 16;
    int b  = blockIdx.z;
    int HWp = H * W;
    const float* xb = x + (size_t)b * 64 * HWp;

    unsigned int* wsl = (unsigned int*)xs;
    for (int p = tid; p < NP; p += 256) {
        int py = p / 18, px = p - py * 18;
        int gy = y0 + py - 1, gx = x0 + px - 1;
        bool ok = (gy >= 0) && (gy < H) && (gx >= 0) && (gx < W);
        const float* gp = xb + (size_t)gy * W + gx;
#pragma unroll 4
        for (int cp = 0; cp < 32; ++cp) {
            float v0 = 0.f, v1 = 0.f;
            if (ok) {
                v0 = gp[(size_t)(2 * cp) * HWp];
                v1 = gp[(size_t)(2 * cp + 1) * HWp];
            }
            unsigned pk = ((unsigned)f2bf(v1) << 16) | (unsigned)f2bf(v0);
            wsl[((cp >> 2) * NP + p) * 4 + (cp & 3)] = pk;
        }
    }
    __syncthreads();

    bool colok = (x0 + lcol) < W;

    for (int ct = 0; ct < COP / 16; ++ct) {
        int co0 = ct * 16;

        bf16x8 a[9][2];
        const unsigned short* wl = wt + ((size_t)co0 + lcol) * 64 + lrow * 8;
#pragma unroll
        for (int t = 0; t < 9; ++t)
#pragma unroll
            for (int kb = 0; kb < 2; ++kb)
                a[t][kb] = *(const bf16x8*)(wl + (size_t)t * COP * 64 + kb * 32);

        float sc[4], sh[4];
#pragma unroll
        for (int rg = 0; rg < 4; ++rg) {
            int co = co0 + lrow * 4 + rg;
            int cc = (co < C_out) ? co : 0;
            if (MODE == 0) { sc[rg] = 1.f; sh[rg] = p0[cc]; }
            else {
                float inv = p0[cc] * rsqrtf(p3[cc] + BN_EPS);
                sc[rg] = inv; sh[rg] = p1[cc] - p2[cc] * inv;
            }
        }

#pragma unroll
        for (int rr = 0; rr < 2; ++rr) {
            int r0 = wid + rr * 8;
            f32x4 acc0 = {0.f, 0.f, 0.f, 0.f};
            f32x4 acc1 = {0.f, 0.f, 0.f, 0.f};
#pragma unroll
            for (int t = 0; t < 9; ++t) {
                int dy = t / 3, dx = t - dy * 3;
#pragma unroll
                for (int kb = 0; kb < 2; ++kb) {
                    int g0 = (kb * 4 + lrow) * NP + (r0 + dy) * 18 + lcol + dx;
                    bf16x8 b0 = *(const bf16x8*)(xs + (size_t)g0 * 8);
                    acc0 = __builtin_amdgcn_mfma_f32_16x16x32_bf16(a[t][kb], b0, acc0, 0, 0, 0);
                    bf16x8 b1 = *(const bf16x8*)(xs + ((size_t)g0 + 4 * 18) * 8);
                    acc1 = __builtin_amdgcn_mfma_f32_16x16x32_bf16(a[t][kb], b1, acc1, 0, 0, 0);
                }
            }
            int yA = y0 + r0, yB = y0 + r0 + 4;
#pragma unroll
            for (int rg = 0; rg < 4; ++rg) {
                int co = co0 + lrow * 4 + rg;
                if (colok && co < C_out) {
                    float* oc = out + (((size_t)b * C_out + co) * H) * W + x0 + lcol;
                    if (yA < H) oc[(size_t)yA * W] = acc0[rg] * sc[rg] + sh[rg];
                    if (yB < H) oc[(size_t)yB * W] = acc1[rg] * sc[rg] + sh[rg];
                }
            }
        }
    }
}

// ---------------------------------------------------------------------------
// conv1x1 v4: register-tiled GEMM, transposed weights (coalesced staging),
// optional K-split across blocks (deep-K small-N: lat2 had 60 blocks x 16
// serial chunks + stride-2KB weight loads -> 59us latency-bound).
// KSPLIT>1: writes raw partials to out (= part buffer), reduced by
// ksplit_reduce. KSPLIT==1: fused epilogue.
// MODE 0: + bias (p0)   MODE 1: BN(g,bt,m,v) + ReLU
// grid: (HW/PXT, KSPLIT, B), block 256
// ---------------------------------------------------------------------------
template<int C_IN, int KSPLIT, int PXT, int MODE>
__global__ __launch_bounds__(256, 2)
void conv1x1_gemm(const float* __restrict__ x, const float* __restrict__ wT,
                  const float* __restrict__ p0, const float* __restrict__ p1,
                  const float* __restrict__ p2, const float* __restrict__ p3,
                  float* __restrict__ out, int HW)
{
    constexpr int KC = 32;
    constexpr int PQ = PXT / 32;
    constexpr int KLEN = C_IN / KSPLIT;
    __shared__ float xs[KC][PXT];
    __shared__ float ws[KC][64];

    int tid = threadIdx.x;
    int tp = tid & 31, tc = tid >> 5;
    int px0 = blockIdx.x * PXT;
    int ks  = blockIdx.y;
    int b   = blockIdx.z;
    const float* xb = x + (size_t)b * C_IN * HW;
    const float4* wt4 = (const float4*)wT;

    float acc[8][PQ];
#pragma unroll
    for (int j = 0; j < 8; ++j)
#pragma unroll
        for (int q = 0; q < PQ; ++q) acc[j][q] = 0.f;

    for (int cc = 0; cc < KLEN; cc += KC) {
        if (cc) __syncthreads();
        int cb = ks * KLEN + cc;
        // stage x chunk: KC x PXT floats as float4 (coalesced)
#pragma unroll
        for (int t = 0; t < KC * PXT / 4 / 256; ++t) {
            int i = tid + t * 256;
            int k = i / (PXT / 4);
            int u = i - k * (PXT / 4);
            int p = px0 + 4 * u;
            float4 v = make_float4(0.f, 0.f, 0.f, 0.f);
            if (p < HW) v = *(const float4*)(xb + (size_t)(cb + k) * HW + p);
            *(float4*)&xs[k][4 * u] = v;
        }
        // stage w chunk from wT[ci][co]: coalesced float4
#pragma unroll
        for (int t = 0; t < 2; ++t) {
            int i = tid + t * 256;
            int k = i >> 4, c4 = i & 15;
            *(float4*)&ws[k][c4 * 4] = wt4[(size_t)(cb + k) * 16 + c4];
        }
        __syncthreads();

#pragma unroll
        for (int k = 0; k < KC; ++k) {
            float xv[PQ];
#pragma unroll
            for (int q = 0; q < PQ; ++q) xv[q] = xs[k][tp + 32 * q];
            float4 wa = *(const float4*)&ws[k][tc * 8];
            float4 wb = *(const float4*)&ws[k][tc * 8 + 4];
            float wv[8] = {wa.x, wa.y, wa.z, wa.w, wb.x, wb.y, wb.z, wb.w};
#pragma unroll
            for (int j = 0; j < 8; ++j)
#pragma unroll
                for (int q = 0; q < PQ; ++q)
                    acc[j][q] = fmaf(wv[j], xv[q], acc[j][q]);
        }
    }

    if (KSPLIT == 1) {
#pragma unroll
        for (int j = 0; j < 8; ++j) {
            int co = tc * 8 + j;
            float scale, shift;
            if (MODE == 0) { scale = 1.f; shift = p0[co]; }
            else {
                float inv = p0[co] * rsqrtf(p3[co] + BN_EPS);
                scale = inv; shift = p1[co] - p2[co] * inv;
            }
            float* op = out + ((size_t)(b * 64 + co)) * HW;
#pragma unroll
            for (int q = 0; q < PQ; ++q) {
                int p = px0 + tp + 32 * q;
                if (p < HW) {
                    float r = acc[j][q] * scale + shift;
                    if (MODE == 1) r = fmaxf(r, 0.f);
                    op[p] = r;
                }
            }
        }
    } else {
#pragma unroll
        for (int j = 0; j < 8; ++j) {
            int co = tc * 8 + j;
            float* op = out + (((size_t)(ks * 4 + b) * 64 + co)) * HW;
#pragma unroll
            for (int q = 0; q < PQ; ++q) {
                int p = px0 + tp + 32 * q;
                if (p < HW) op[p] = acc[j][q];
            }
        }
    }
}

// ---------------------------------------------------------------------------
// K-split reduce + bias: out[i] = sum_ks part[ks][i] + bias[co]
// grid: N4/256 blocks (N4 = B*64*HW/4, exact)
// ---------------------------------------------------------------------------
template<int KSPLIT>
__global__ __launch_bounds__(256)
void ksplit_reduce(const float* __restrict__ part, const float* __restrict__ bias,
                   float* __restrict__ out, int HW, int N4)
{
    int i = blockIdx.x * 256 + threadIdx.x;
    if (i >= N4) return;
    size_t base = (size_t)i * 4;
    int co = (int)((base / (size_t)HW) & 63);
    size_t stride = (size_t)HW << 8;           // 4*64*HW
    float4 s = *(const float4*)(part + base);
#pragma unroll
    for (int ks = 1; ks < KSPLIT; ++ks) {
        float4 t = *(const float4*)(part + (size_t)ks * stride + base);
        s.x += t.x; s.y += t.y; s.z += t.z; s.w += t.w;
    }
    float bv = bias[co];
    s.x += bv; s.y += bv; s.z += bv; s.w += bv;
    *(float4*)(out + base) = s;
}

// ---------------------------------------------------------------------------
// CARAFE v3 (R6 version — known good)
// grid: (2w/16, 2h/16, B), block 256
// ---------------------------------------------------------------------------
__global__ __launch_bounds__(256, 4)
void carafe_kernel(const float* __restrict__ src, const float* __restrict__ logits,
                   float* __restrict__ dst, int h, int w)
{
    constexpr int SW = 12, NPX = 144, CS = 68;
    __shared__ float ls[NPX * CS];

    int tid = threadIdx.x;
    int x0 = blockIdx.x * 16, y0 = blockIdx.y * 16;
    int b = blockIdx.z;
    int H = 2 * h, W = 2 * w;
    int xs0 = (x0 >> 1) - 2, ys0 = (y0 >> 1) - 2;
    size_t hw = (size_t)h * w;
    const float* sb = src + (size_t)b * 64 * hw;

    for (int i = tid; i < NPX * 64; i += 256) {
        int c = i / NPX, p = i - c * NPX;
        int yy = p / SW, xx = p - yy * SW;
        int sy = ys0 + yy, sx = xs0 + xx;
        float v = 0.f;
        if (sy >= 0 && sy < h && sx >= 0 && sx < w)
            v = sb[(size_t)c * hw + (size_t)sy * w + sx];
        ls[p * CS + c] = v;
    }
    __syncthreads();

    int lx = tid & 15, ty = tid >> 4;
    int x = x0 + lx, y = y0 + ty;
    int xw = x >> 1, yh = y >> 1;
    int par = (y & 1) * 2 + (x & 1);

    const float* lp = logits + ((size_t)(b * 100 + par) * h + yh) * w + xw;
    float l[25];
    float mx = -1e30f;
#pragma unroll
    for (int k = 0; k < 25; ++k) {
        l[k] = lp[(size_t)(4 * k) * hw];
        mx = fmaxf(mx, l[k]);
    }
    float s = 0.f;
#pragma unroll
    for (int k = 0; k < 25; ++k) {
        l[k] = __expf(l[k] - mx);
        s += l[k];
    }
    float invs = 1.f / s;
#pragma unroll
    for (int k = 0; k < 25; ++k) l[k] *= invs;

    int pb = (yh - ys0 - 2) * SW + (xw - xs0 - 2);

#pragma unroll 1
    for (int cg = 0; cg < 4; ++cg) {
        float acc[16];
#pragma unroll
        for (int c = 0; c < 16; ++c) acc[c] = 0.f;
#pragma unroll
        for (int k = 0; k < 25; ++k) {
            int ti = k / 5, tj = k - ti * 5;
            const float* q = &ls[(pb + ti * SW + tj) * CS + cg * 16];
            float wk = l[k];
#pragma unroll
            for (int c = 0; c < 16; ++c)
                acc[c] = fmaf(wk, q[c], acc[c]);
        }
        float* dp = dst + (((size_t)(b * 64 + cg * 16)) * H + y) * W + x;
#pragma unroll
        for (int c = 0; c < 16; ++c)
            dp[(size_t)c * H * W] += acc[c];
    }
}

// ---------------------------------------------------------------------------
extern "C" void kernel_launch(void* const* d_in, const int* in_sizes, int n_in,
                              void* d_out, int out_size, void* d_ws, size_t ws_size,
                              hipStream_t stream)
{
    const float* x0      = (const float*)d_in[0];
    const float* lat0_w  = (const float*)d_in[1];
    const float* lat0_b  = (const float*)d_in[2];
    const float* fpn0_w  = (const float*)d_in[3];
    const float* fpn0_b  = (const float*)d_in[4];
    const float* x1      = (const float*)d_in[5];
    const float* lat1_w  = (const float*)d_in[6];
    const float* lat1_b  = (const float*)d_in[7];
    const float* fpn1_w  = (const float*)d_in[8];
    const float* fpn1_b  = (const float*)d_in[9];
    const float* x2      = (const float*)d_in[10];
    const float* lat2_w  = (const float*)d_in[11];
    const float* lat2_b  = (const float*)d_in[12];
    const float* fpn2_w  = (const float*)d_in[13];
    const float* fpn2_b  = (const float*)d_in[14];
    const float* u0_comp_w = (const float*)d_in[15];
    const float* u0_enc_w  = (const float*)d_in[16];
    const float* u0_comp_g  = (const float*)d_in[17];
    const float* u0_comp_bt = (const float*)d_in[18];
    const float* u0_comp_m  = (const float*)d_in[19];
    const float* u0_comp_v  = (const float*)d_in[20];
    const float* u0_enc_g   = (const float*)d_in[21];
    const float* u0_enc_bt  = (const float*)d_in[22];
    const float* u0_enc_m   = (const float*)d_in[23];
    const float* u0_enc_v   = (const float*)d_in[24];
    const float* u1_comp_w = (const float*)d_in[25];
    const float* u1_enc_w  = (const float*)d_in[26];
    const float* u1_comp_g  = (const float*)d_in[27];
    const float* u1_comp_bt = (const float*)d_in[28];
    const float* u1_comp_m  = (const float*)d_in[29];
    const float* u1_comp_v  = (const float*)d_in[30];
    const float* u1_enc_g   = (const float*)d_in[31];
    const float* u1_enc_bt  = (const float*)d_in[32];
    const float* u1_enc_m   = (const float*)d_in[33];
    const float* u1_enc_v   = (const float*)d_in[34];

    float* out = (float*)d_out;
    const size_t OUT0 = 4ull * 64 * 96 * 160;   // 3,932,160
    const size_t OUT1 = 4ull * 64 * 48 * 80;    //   983,040
    const size_t OUT2 = 4ull * 64 * 24 * 40;    //   245,760
    float* out0 = out;
    float* out1 = out + OUT0;
    float* out2 = out + OUT0 + OUT1;

    float* lat0 = (float*)d_ws;
    float* lat1 = lat0 + OUT0;
    float* lat2 = lat1 + OUT1;
    unsigned short* wtb = (unsigned short*)(lat2 + OUT2);   // 239,616 bf16
    unsigned short* wt_fpn0 = wtb;
    unsigned short* wt_fpn1 = wtb + 36864;
    unsigned short* wt_fpn2 = wtb + 73728;
    unsigned short* wt_enc0 = wtb + 110592;
    unsigned short* wt_enc1 = wtb + 175104;
    float* wT = (float*)(wtb + 239616);                     // 65,536 fp32
    float* wT_lat0  = wT;
    float* wT_lat1  = wT + 8192;
    float* wT_lat2  = wT + 24576;
    float* wT_comp0 = wT + 57344;
    float* wT_comp1 = wT + 61440;
    // out0 region doubles as scratch (overwritten last by fpn0 conv):
    float* part = out0;          // K-split partials (<= 1.97M floats), stage 1 only
    float* comp = out0;          // comp logits (stages 2-3)
    float* enc  = out0 + OUT1;   // enc logits

    dim3 blk(256);

    // 0) weight transforms
    wt_transform<<<dim3(252, 5), blk, 0, stream>>>(
        fpn0_w, fpn1_w, fpn2_w, u0_enc_w, u1_enc_w, wtb);
    w1_transpose<<<dim3(128, 5), blk, 0, stream>>>(
        lat0_w, lat1_w, lat2_w, u0_comp_w, u1_comp_w, wT);

    // 1) lateral 1x1 convs + bias
    conv1x1_gemm<128, 1, 256, 0><<<dim3(60, 1, 4), blk, 0, stream>>>(
        x0, wT_lat0, lat0_b, nullptr, nullptr, nullptr, lat0, 96 * 160);
    conv1x1_gemm<256, 2, 128, 0><<<dim3(30, 2, 4), blk, 0, stream>>>(
        x1, wT_lat1, nullptr, nullptr, nullptr, nullptr, part, 48 * 80);
    ksplit_reduce<2><<<dim3(960), blk, 0, stream>>>(part, lat1_b, lat1, 48 * 80, 245760);
    conv1x1_gemm<512, 8, 64, 0><<<dim3(15, 8, 4), blk, 0, stream>>>(
        x2, wT_lat2, nullptr, nullptr, nullptr, nullptr, part, 24 * 40);
    ksplit_reduce<8><<<dim3(240), blk, 0, stream>>>(part, lat2_b, lat2, 24 * 40, 61440);

    // 2) CARAFE u1: lat1 += carafe(lat2)
    conv1x1_gemm<64, 1, 32, 1><<<dim3(30, 1, 4), blk, 0, stream>>>(
        lat2, wT_comp1, u1_comp_g, u1_comp_bt, u1_comp_m, u1_comp_v, comp, 24 * 40);
    conv3x3_mfma<112, 1><<<dim3(3, 2, 4), blk, 0, stream>>>(
        comp, wt_enc1, u1_enc_g, u1_enc_bt, u1_enc_m, u1_enc_v, enc, 24, 40, 100);
    carafe_kernel<<<dim3(5, 3, 4), blk, 0, stream>>>(lat2, enc, lat1, 24, 40);

    // 3) CARAFE u0: lat0 += carafe(lat1)
    conv1x1_gemm<64, 1, 128, 1><<<dim3(30, 1, 4), blk, 0, stream>>>(
        lat1, wT_comp0, u0_comp_g, u0_comp_bt, u0_comp_m, u0_comp_v, comp, 48 * 80);
    conv3x3_mfma<112, 1><<<dim3(5, 3, 4), blk, 0, stream>>>(
        comp, wt_enc0, u0_enc_g, u0_enc_bt, u0_enc_m, u0_enc_v, enc, 48, 80, 100);
    carafe_kernel<<<dim3(10, 6, 4), blk, 0, stream>>>(lat1, enc, lat0, 48, 80);

    // 4) output 3x3 convs + bias  (fpn0 LAST — its region held scratch)
    conv3x3_mfma<64, 0><<<dim3(5, 3, 4), blk, 0, stream>>>(
        lat1, wt_fpn1, fpn1_b, nullptr, nullptr, nullptr, out1, 48, 80, 64);
    conv3x3_mfma<64, 0><<<dim3(3, 2, 4), blk, 0, stream>>>(
        lat2, wt_fpn2, fpn2_b, nullptr, nullptr, nullptr, out2, 24, 40, 64);
    conv3x3_mfma<64, 0><<<dim3(10, 6, 4), blk, 0, stream>>>(
        lat0, wt_fpn0, fpn0_b, nullptr, nullptr, nullptr, out0, 96, 160, 64);
}

// Round 10
// 503.785 us; speedup vs baseline: 1.2201x; 1.0956x over previous
//
#include <hip/hip_runtime.h>

#define BN_EPS 1e-5f

typedef __attribute__((ext_vector_type(8))) short bf16x8;
typedef __attribute__((ext_vector_type(4))) float f32x4;

__device__ __forceinline__ unsigned short f2bf(float f) {
    unsigned u = __float_as_uint(f);
    return (unsigned short)((u + 0x7fffu + ((u >> 16) & 1u)) >> 16);   // RNE
}

// ---------------------------------------------------------------------------
// Weight prep (ONE launch):
// z 0..2: fpn0/1/2 conv3x3 -> wt[tap][co64][ci] bf16
// z 3..4: enc0/1  conv3x3 -> wt[tap][co112][ci] bf16 (zero-pad co 100->112)
// z 5..9: lat0/lat1/lat2/comp0/comp1 1x1 -> straight bf16 cast [co][ci]
// grid (252, 10), block 256
// ---------------------------------------------------------------------------
__global__ __launch_bounds__(256)
void prep_weights(const float* __restrict__ w0, const float* __restrict__ w1,
                  const float* __restrict__ w2, const float* __restrict__ w3,
                  const float* __restrict__ w4, unsigned short* __restrict__ dst,
                  const float* __restrict__ v0, const float* __restrict__ v1,
                  const float* __restrict__ v2, const float* __restrict__ v3,
                  const float* __restrict__ v4, unsigned short* __restrict__ dst1)
{
    int z = blockIdx.y;
    int i = blockIdx.x * 256 + threadIdx.x;
    if (z < 5) {
        const float* src; unsigned short* d; int C_out, COP;
        if (z < 3) {
            COP = 64; C_out = 64;
            src = (z == 0) ? w0 : (z == 1 ? w1 : w2);
            d = dst + z * 36864;
            if (i >= 36864) return;
        } else {
            COP = 112; C_out = 100;
            src = (z == 3) ? w3 : w4;
            d = dst + 110592 + (z - 3) * 64512;
            if (i >= 64512) return;
        }
        int tap = i / (COP * 64);
        int rem = i - tap * (COP * 64);
        int co = rem >> 6, ci = rem & 63;
        float v = (co < C_out) ? src[((size_t)co * 64 + ci) * 9 + tap] : 0.f;
        d[i] = f2bf(v);
    } else {
        int zz = z - 5;
        const float* s; int n; int off;
        if (zz == 0)      { s = v0; n = 8192;  off = 0; }
        else if (zz == 1) { s = v1; n = 16384; off = 8192; }
        else if (zz == 2) { s = v2; n = 32768; off = 24576; }
        else if (zz == 3) { s = v3; n = 4096;  off = 57344; }
        else              { s = v4; n = 4096;  off = 61440; }
        if (i >= n) return;
        dst1[off + i] = f2bf(s[i]);
    }
}

// ---------------------------------------------------------------------------
// conv3x3 via bf16 MFMA (16x16x32), pad=1, C_in=64, fp32 accumulate.
// (R5 version — known good)
// grid: (ceil(W/16), ceil(H/16), B), block 256
// ---------------------------------------------------------------------------
template<int COP, int MODE>
__global__ __launch_bounds__(256, 4)
void conv3x3_mfma(const float* __restrict__ x, const unsigned short* __restrict__ wt,
                  const float* __restrict__ p0, const float* __restrict__ p1,
                  const float* __restrict__ p2, const float* __restrict__ p3,
                  float* __restrict__ out, int H, int W, int C_out)
{
    constexpr int NP = 324;
    __shared__ unsigned short xs[8 * NP * 8];

    int tid  = threadIdx.x;
    int lane = tid & 63, wid = tid >> 6;
    int lrow = lane >> 4, lcol = lane & 15;
    int x0 = blockIdx.x * 16, y0 = blockIdx.y * 16;
    int b  = blockIdx.z;
    int HWp = H * W;
    const float* xb = x + (size_t)b * 64 * HWp;

    unsigned int* wsl = (unsigned int*)xs;
    for (int p = tid; p < NP; p += 256) {
        int py = p / 18, px = p - py * 18;
        int gy = y0 + py - 1, gx = x0 + px - 1;
        bool ok = (gy >= 0) && (gy < H) && (gx >= 0) && (gx < W);
        const float* gp = xb + (size_t)gy * W + gx;
#pragma unroll 4
        for (int cp = 0; cp < 32; ++cp) {
            float v0 = 0.f, v1 = 0.f;
            if (ok) {
                v0 = gp[(size_t)(2 * cp) * HWp];
                v1 = gp[(size_t)(2 * cp + 1) * HWp];
            }
            unsigned pk = ((unsigned)f2bf(v1) << 16) | (unsigned)f2bf(v0);
            wsl[((cp >> 2) * NP + p) * 4 + (cp & 3)] = pk;
        }
    }
    __syncthreads();

    bool colok = (x0 + lcol) < W;

    for (int ct = 0; ct < COP / 16; ++ct) {
        int co0 = ct * 16;

        bf16x8 a[9][2];
        const unsigned short* wl = wt + ((size_t)co0 + lcol) * 64 + lrow * 8;
#pragma unroll
        for (int t = 0; t < 9; ++t)
#pragma unroll
            for (int kb = 0; kb < 2; ++kb)
                a[t][kb] = *(const bf16x8*)(wl + (size_t)t * COP * 64 + kb * 32);

        float sc[4], sh[4];
#pragma unroll
        for (int rg = 0; rg < 4; ++rg) {
            int co = co0 + lrow * 4 + rg;
            int cc = (co < C_out) ? co : 0;
            if (MODE == 0) { sc[rg] = 1.f; sh[rg] = p0[cc]; }
            else {
                float inv = p0[cc] * rsqrtf(p3[cc] + BN_EPS);
                sc[rg] = inv; sh[rg] = p1[cc] - p2[cc] * inv;
            }
        }

#pragma unroll
        for (int rr = 0; rr < 2; ++rr) {
            int r0 = wid + rr * 8;
            f32x4 acc0 = {0.f, 0.f, 0.f, 0.f};
            f32x4 acc1 = {0.f, 0.f, 0.f, 0.f};
#pragma unroll
            for (int t = 0; t < 9; ++t) {
                int dy = t / 3, dx = t - dy * 3;
#pragma unroll
                for (int kb = 0; kb < 2; ++kb) {
                    int g0 = (kb * 4 + lrow) * NP + (r0 + dy) * 18 + lcol + dx;
                    bf16x8 b0 = *(const bf16x8*)(xs + (size_t)g0 * 8);
                    acc0 = __builtin_amdgcn_mfma_f32_16x16x32_bf16(a[t][kb], b0, acc0, 0, 0, 0);
                    bf16x8 b1 = *(const bf16x8*)(xs + ((size_t)g0 + 4 * 18) * 8);
                    acc1 = __builtin_amdgcn_mfma_f32_16x16x32_bf16(a[t][kb], b1, acc1, 0, 0, 0);
                }
            }
            int yA = y0 + r0, yB = y0 + r0 + 4;
#pragma unroll
            for (int rg = 0; rg < 4; ++rg) {
                int co = co0 + lrow * 4 + rg;
                if (colok && co < C_out) {
                    float* oc = out + (((size_t)b * C_out + co) * H) * W + x0 + lcol;
                    if (yA < H) oc[(size_t)yA * W] = acc0[rg] * sc[rg] + sh[rg];
                    if (yB < H) oc[(size_t)yB * W] = acc1[rg] * sc[rg] + sh[rg];
                }
            }
        }
    }
}

// ---------------------------------------------------------------------------
// conv1x1 v5: bf16 MFMA GEMM. M=64 co (4 m-tiles, one per wave), K=C_IN in
// 32-chunks, N=NPX pixels (NT 16-px tiles). fp32 VALU path capped lat0 at
// 54us (26us FMA floor); MFMA makes it memory-bound (~8us). A-frag: bf16
// weights [co][ci] 16B/lane (layout verified in conv3x3_mfma); B: x staged
// fp32->bf16 in LDS px-major 8-ci granules (ds_read_b128, full bank spread).
// KSPLIT>1: raw fp32 partials to part buffer (ksplit_reduce adds bias).
// MODE 0: +bias(p0)   MODE 1: BN(g,bt,m,v)+ReLU
// grid: (HW/NPX, KSPLIT, B), block 256.  Requires HW % NPX == 0.
// ---------------------------------------------------------------------------
template<int C_IN, int KSPLIT, int NPX, int MODE>
__global__ __launch_bounds__(256, 4)
void conv1x1_mfma(const float* __restrict__ x, const unsigned short* __restrict__ wb,
                  const float* __restrict__ p0, const float* __restrict__ p1,
                  const float* __restrict__ p2, const float* __restrict__ p3,
                  float* __restrict__ out, int HW)
{
    constexpr int NT = NPX / 16;
    constexpr int KLEN = C_IN / KSPLIT;
    __shared__ __align__(16) unsigned short xs[4][NPX][8];   // 32ci x NPX bf16

    int tid = threadIdx.x;
    int lane = tid & 63, wid = tid >> 6;
    int lrow = lane >> 4, lcol = lane & 15;
    int px0 = blockIdx.x * NPX;
    int ks  = blockIdx.y;
    int b   = blockIdx.z;
    const float* xb = x + (size_t)b * C_IN * HW + px0;

    f32x4 acc[NT];
#pragma unroll
    for (int nt = 0; nt < NT; ++nt) acc[nt] = (f32x4){0.f, 0.f, 0.f, 0.f};

    for (int cc = 0; cc < KLEN; cc += 32) {
        if (cc) __syncthreads();
        int cb = ks * KLEN + cc;
        // stage 32ci x NPX px, fp32 -> packed bf16 pairs
#pragma unroll
        for (int t = 0; t < NPX / 16; ++t) {
            int i = tid + t * 256;
            int px = i & (NPX - 1);
            int cp = i / NPX;                        // ci pair 0..15
            float v0 = xb[(size_t)(cb + 2 * cp) * HW + px];
            float v1 = xb[(size_t)(cb + 2 * cp + 1) * HW + px];
            unsigned pk = ((unsigned)f2bf(v1) << 16) | (unsigned)f2bf(v0);
            ((unsigned*)&xs[cp >> 2][px][0])[cp & 3] = pk;
        }
        __syncthreads();

        bf16x8 a = *(const bf16x8*)(wb + (size_t)(wid * 16 + lcol) * C_IN + cb + lrow * 8);
#pragma unroll
        for (int nt = 0; nt < NT; ++nt) {
            bf16x8 bf = *(const bf16x8*)&xs[lrow][nt * 16 + lcol][0];
            acc[nt] = __builtin_amdgcn_mfma_f32_16x16x32_bf16(a, bf, acc[nt], 0, 0, 0);
        }
    }

    if (KSPLIT == 1) {
#pragma unroll
        for (int rg = 0; rg < 4; ++rg) {
            int co = wid * 16 + lrow * 4 + rg;
            float scale, shift;
            if (MODE == 0) { scale = 1.f; shift = p0[co]; }
            else {
                float inv = p0[co] * rsqrtf(p3[co] + BN_EPS);
                scale = inv; shift = p1[co] - p2[co] * inv;
            }
            float* op = out + ((size_t)(b * 64 + co)) * HW + px0;
#pragma unroll
            for (int nt = 0; nt < NT; ++nt) {
                float r = acc[nt][rg] * scale + shift;
                if (MODE == 1) r = fmaxf(r, 0.f);
                op[nt * 16 + lcol] = r;
            }
        }
    } else {
#pragma unroll
        for (int rg = 0; rg < 4; ++rg) {
            int co = wid * 16 + lrow * 4 + rg;
            float* op = out + (((size_t)(ks * 4 + b)) * 64 + co) * HW + px0;
#pragma unroll
            for (int nt = 0; nt < NT; ++nt)
                op[nt * 16 + lcol] = acc[nt][rg];
        }
    }
}

// ---------------------------------------------------------------------------
// K-split reduce + bias: out[i] = sum_ks part[ks][i] + bias[co]
// grid: N4/256 blocks (N4 = B*64*HW/4, exact)
// ---------------------------------------------------------------------------
template<int KSPLIT>
__global__ __launch_bounds__(256)
void ksplit_reduce(const float* __restrict__ part, const float* __restrict__ bias,
                   float* __restrict__ out, int HW, int N4)
{
    int i = blockIdx.x * 256 + threadIdx.x;
    if (i >= N4) return;
    size_t base = (size_t)i * 4;
    int co = (int)((base / (size_t)HW) & 63);
    size_t stride = (size_t)HW << 8;           // 4*64*HW
    float4 s = *(const float4*)(part + base);
#pragma unroll
    for (int ks = 1; ks < KSPLIT; ++ks) {
        float4 t = *(const float4*)(part + (size_t)ks * stride + base);
        s.x += t.x; s.y += t.y; s.z += t.z; s.w += t.w;
    }
    float bv = bias[co];
    s.x += bv; s.y += bv; s.z += bv; s.w += bv;
    *(float4*)(out + base) = s;
}

// ---------------------------------------------------------------------------
// CARAFE v3 (R6 version — known good)
// grid: (2w/16, 2h/16, B), block 256
// ---------------------------------------------------------------------------
__global__ __launch_bounds__(256, 4)
void carafe_kernel(const float* __restrict__ src, const float* __restrict__ logits,
                   float* __restrict__ dst, int h, int w)
{
    constexpr int SW = 12, NPX = 144, CS = 68;
    __shared__ float ls[NPX * CS];

    int tid = threadIdx.x;
    int x0 = blockIdx.x * 16, y0 = blockIdx.y * 16;
    int b = blockIdx.z;
    int H = 2 * h, W = 2 * w;
    int xs0 = (x0 >> 1) - 2, ys0 = (y0 >> 1) - 2;
    size_t hw = (size_t)h * w;
    const float* sb = src + (size_t)b * 64 * hw;

    for (int i = tid; i < NPX * 64; i += 256) {
        int c = i / NPX, p = i - c * NPX;
        int yy = p / SW, xx = p - yy * SW;
        int sy = ys0 + yy, sx = xs0 + xx;
        float v = 0.f;
        if (sy >= 0 && sy < h && sx >= 0 && sx < w)
            v = sb[(size_t)c * hw + (size_t)sy * w + sx];
        ls[p * CS + c] = v;
    }
    __syncthreads();

    int lx = tid & 15, ty = tid >> 4;
    int x = x0 + lx, y = y0 + ty;
    int xw = x >> 1, yh = y >> 1;
    int par = (y & 1) * 2 + (x & 1);

    const float* lp = logits + ((size_t)(b * 100 + par) * h + yh) * w + xw;
    float l[25];
    float mx = -1e30f;
#pragma unroll
    for (int k = 0; k < 25; ++k) {
        l[k] = lp[(size_t)(4 * k) * hw];
        mx = fmaxf(mx, l[k]);
    }
    float s = 0.f;
#pragma unroll
    for (int k = 0; k < 25; ++k) {
        l[k] = __expf(l[k] - mx);
        s += l[k];
    }
    float invs = 1.f / s;
#pragma unroll
    for (int k = 0; k < 25; ++k) l[k] *= invs;

    int pb = (yh - ys0 - 2) * SW + (xw - xs0 - 2);

#pragma unroll 1
    for (int cg = 0; cg < 4; ++cg) {
        float acc[16];
#pragma unroll
        for (int c = 0; c < 16; ++c) acc[c] = 0.f;
#pragma unroll
        for (int k = 0; k < 25; ++k) {
            int ti = k / 5, tj = k - ti * 5;
            const float* q = &ls[(pb + ti * SW + tj) * CS + cg * 16];
            float wk = l[k];
#pragma unroll
            for (int c = 0; c < 16; ++c)
                acc[c] = fmaf(wk, q[c], acc[c]);
        }
        float* dp = dst + (((size_t)(b * 64 + cg * 16)) * H + y) * W + x;
#pragma unroll
        for (int c = 0; c < 16; ++c)
            dp[(size_t)c * H * W] += acc[c];
    }
}

// ---------------------------------------------------------------------------
extern "C" void kernel_launch(void* const* d_in, const int* in_sizes, int n_in,
                              void* d_out, int out_size, void* d_ws, size_t ws_size,
                              hipStream_t stream)
{
    const float* x0      = (const float*)d_in[0];
    const float* lat0_w  = (const float*)d_in[1];
    const float* lat0_b  = (const float*)d_in[2];
    const float* fpn0_w  = (const float*)d_in[3];
    const float* fpn0_b  = (const float*)d_in[4];
    const float* x1      = (const float*)d_in[5];
    const float* lat1_w  = (const float*)d_in[6];
    const float* lat1_b  = (const float*)d_in[7];
    const float* fpn1_w  = (const float*)d_in[8];
    const float* fpn1_b  = (const float*)d_in[9];
    const float* x2      = (const float*)d_in[10];
    const float* lat2_w  = (const float*)d_in[11];
    const float* lat2_b  = (const float*)d_in[12];
    const float* fpn2_w  = (const float*)d_in[13];
    const float* fpn2_b  = (const float*)d_in[14];
    const float* u0_comp_w = (const float*)d_in[15];
    const float* u0_enc_w  = (const float*)d_in[16];
    const float* u0_comp_g  = (const float*)d_in[17];
    const float* u0_comp_bt = (const float*)d_in[18];
    const float* u0_comp_m  = (const float*)d_in[19];
    const float* u0_comp_v  = (const float*)d_in[20];
    const float* u0_enc_g   = (const float*)d_in[21];
    const float* u0_enc_bt  = (const float*)d_in[22];
    const float* u0_enc_m   = (const float*)d_in[23];
    const float* u0_enc_v   = (const float*)d_in[24];
    const float* u1_comp_w = (const float*)d_in[25];
    const float* u1_enc_w  = (const float*)d_in[26];
    const float* u1_comp_g  = (const float*)d_in[27];
    const float* u1_comp_bt = (const float*)d_in[28];
    const float* u1_comp_m  = (const float*)d_in[29];
    const float* u1_comp_v  = (const float*)d_in[30];
    const float* u1_enc_g   = (const float*)d_in[31];
    const float* u1_enc_bt  = (const float*)d_in[32];
    const float* u1_enc_m   = (const float*)d_in[33];
    const float* u1_enc_v   = (const float*)d_in[34];

    float* out = (float*)d_out;
    const size_t OUT0 = 4ull * 64 * 96 * 160;   // 3,932,160
    const size_t OUT1 = 4ull * 64 * 48 * 80;    //   983,040
    const size_t OUT2 = 4ull * 64 * 24 * 40;    //   245,760
    float* out0 = out;
    float* out1 = out + OUT0;
    float* out2 = out + OUT0 + OUT1;

    float* lat0 = (float*)d_ws;
    float* lat1 = lat0 + OUT0;
    float* lat2 = lat1 + OUT1;
    unsigned short* wtb = (unsigned short*)(lat2 + OUT2);   // 239,616 bf16
    unsigned short* wt_fpn0 = wtb;
    unsigned short* wt_fpn1 = wtb + 36864;
    unsigned short* wt_fpn2 = wtb + 73728;
    unsigned short* wt_enc0 = wtb + 110592;
    unsigned short* wt_enc1 = wtb + 175104;
    unsigned short* wb = wtb + 239616;                      // 65,536 bf16 (1x1)
    unsigned short* wb_lat0  = wb;
    unsigned short* wb_lat1  = wb + 8192;
    unsigned short* wb_lat2  = wb + 24576;
    unsigned short* wb_comp0 = wb + 57344;
    unsigned short* wb_comp1 = wb + 61440;
    // out0 region doubles as scratch (overwritten last by fpn0 conv):
    float* part = out0;          // K-split partials (stage 1 only)
    float* comp = out0;          // comp logits (stages 2-3)
    float* enc  = out0 + OUT1;   // enc logits

    dim3 blk(256);

    // 0) weight prep (conv3x3 bf16 transform + 1x1 bf16 cast, one launch)
    prep_weights<<<dim3(252, 10), blk, 0, stream>>>(
        fpn0_w, fpn1_w, fpn2_w, u0_enc_w, u1_enc_w, wtb,
        lat0_w, lat1_w, lat2_w, u0_comp_w, u1_comp_w, wb);

    // 1) lateral 1x1 convs + bias (MFMA)
    conv1x1_mfma<128, 1, 128, 0><<<dim3(120, 1, 4), blk, 0, stream>>>(
        x0, wb_lat0, lat0_b, nullptr, nullptr, nullptr, lat0, 96 * 160);
    conv1x1_mfma<256, 2, 128, 0><<<dim3(30, 2, 4), blk, 0, stream>>>(
        x1, wb_lat1, nullptr, nullptr, nullptr, nullptr, part, 48 * 80);
    ksplit_reduce<2><<<dim3(960), blk, 0, stream>>>(part, lat1_b, lat1, 48 * 80, 245760);
    conv1x1_mfma<512, 4, 64, 0><<<dim3(15, 4, 4), blk, 0, stream>>>(
        x2, wb_lat2, nullptr, nullptr, nullptr, nullptr, part, 24 * 40);
    ksplit_reduce<4><<<dim3(240), blk, 0, stream>>>(part, lat2_b, lat2, 24 * 40, 61440);

    // 2) CARAFE u1: lat1 += carafe(lat2)
    conv1x1_mfma<64, 1, 64, 1><<<dim3(15, 1, 4), blk, 0, stream>>>(
        lat2, wb_comp1, u1_comp_g, u1_comp_bt, u1_comp_m, u1_comp_v, comp, 24 * 40);
    conv3x3_mfma<112, 1><<<dim3(3, 2, 4), blk, 0, stream>>>(
        comp, wt_enc1, u1_enc_g, u1_enc_bt, u1_enc_m, u1_enc_v, enc, 24, 40, 100);
    carafe_kernel<<<dim3(5, 3, 4), blk, 0, stream>>>(lat2, enc, lat1, 24, 40);

    // 3) CARAFE u0: lat0 += carafe(lat1)
    conv1x1_mfma<64, 1, 128, 1><<<dim3(30, 1, 4), blk, 0, stream>>>(
        lat1, wb_comp0, u0_comp_g, u0_comp_bt, u0_comp_m, u0_comp_v, comp, 48 * 80);
    conv3x3_mfma<112, 1><<<dim3(5, 3, 4), blk, 0, stream>>>(
        comp, wt_enc0, u0_enc_g, u0_enc_bt, u0_enc_m, u0_enc_v, enc, 48, 80, 100);
    carafe_kernel<<<dim3(10, 6, 4), blk, 0, stream>>>(lat1, enc, lat0, 48, 80);

    // 4) output 3x3 convs + bias  (fpn0 LAST — its region held scratch)
    conv3x3_mfma<64, 0><<<dim3(5, 3, 4), blk, 0, stream>>>(
        lat1, wt_fpn1, fpn1_b, nullptr, nullptr, nullptr, out1, 48, 80, 64);
    conv3x3_mfma<64, 0><<<dim3(3, 2, 4), blk, 0, stream>>>(
        lat2, wt_fpn2, fpn2_b, nullptr, nullptr, nullptr, out2, 24, 40, 64);
    conv3x3_mfma<64, 0><<<dim3(10, 6, 4), blk, 0, stream>>>(
        lat0, wt_fpn0, fpn0_b, nullptr, nullptr, nullptr, out0, 96, 160, 64);
}

// Round 11
// 435.921 us; speedup vs baseline: 1.4101x; 1.1557x over previous
//
#include <hip/hip_runtime.h>

#define BN_EPS 1e-5f

typedef __attribute__((ext_vector_type(8))) short bf16x8;
typedef __attribute__((ext_vector_type(4))) float f32x4;

__device__ __forceinline__ unsigned short f2bf(float f) {
    unsigned u = __float_as_uint(f);
    return (unsigned short)((u + 0x7fffu + ((u >> 16) & 1u)) >> 16);   // RNE
}

// ---------------------------------------------------------------------------
// Weight prep (ONE launch):
// z 0..2: fpn0/1/2 conv3x3 -> wt[tap][co64][ci] bf16
// z 3..4: enc0/1  conv3x3 -> wt[tap][co112][ci] bf16 (zero-pad co 100->112)
// z 5..9: lat0/lat1/lat2/comp0/comp1 1x1 -> straight bf16 cast [co][ci]
// grid (252, 10), block 256
// ---------------------------------------------------------------------------
__global__ __launch_bounds__(256)
void prep_weights(const float* __restrict__ w0, const float* __restrict__ w1,
                  const float* __restrict__ w2, const float* __restrict__ w3,
                  const float* __restrict__ w4, unsigned short* __restrict__ dst,
                  const float* __restrict__ v0, const float* __restrict__ v1,
                  const float* __restrict__ v2, const float* __restrict__ v3,
                  const float* __restrict__ v4, unsigned short* __restrict__ dst1)
{
    int z = blockIdx.y;
    int i = blockIdx.x * 256 + threadIdx.x;
    if (z < 5) {
        const float* src; unsigned short* d; int C_out, COP;
        if (z < 3) {
            COP = 64; C_out = 64;
            src = (z == 0) ? w0 : (z == 1 ? w1 : w2);
            d = dst + z * 36864;
            if (i >= 36864) return;
        } else {
            COP = 112; C_out = 100;
            src = (z == 3) ? w3 : w4;
            d = dst + 110592 + (z - 3) * 64512;
            if (i >= 64512) return;
        }
        int tap = i / (COP * 64);
        int rem = i - tap * (COP * 64);
        int co = rem >> 6, ci = rem & 63;
        float v = (co < C_out) ? src[((size_t)co * 64 + ci) * 9 + tap] : 0.f;
        d[i] = f2bf(v);
    } else {
        int zz = z - 5;
        const float* s; int n; int off;
        if (zz == 0)      { s = v0; n = 8192;  off = 0; }
        else if (zz == 1) { s = v1; n = 16384; off = 8192; }
        else if (zz == 2) { s = v2; n = 32768; off = 24576; }
        else if (zz == 3) { s = v3; n = 4096;  off = 57344; }
        else              { s = v4; n = 4096;  off = 61440; }
        if (i >= n) return;
        dst1[off + i] = f2bf(s[i]);
    }
}

// ---------------------------------------------------------------------------
// conv3x3 via bf16 MFMA (16x16x32), pad=1, C_in=64, fp32 accumulate.
// v11: CSPLIT co-tile split across blocks — R10 showed enc0 at 60 blocks /
// 2.3% occupancy / 51us, pure parallelism starvation. Each block stages the
// same halo but computes CT/CSPLIT co-tiles; staging re-fetch is cheap vs
// 5-7x more latency-hiding blocks, and VGPR drops (fewer live A-frags).
// grid: (ceil(W/16), ceil(H/16), B * CSPLIT), block 256
// ---------------------------------------------------------------------------
template<int COP, int CSPLIT, int MODE>
__global__ __launch_bounds__(256, 4)
void conv3x3_mfma(const float* __restrict__ x, const unsigned short* __restrict__ wt,
                  const float* __restrict__ p0, const float* __restrict__ p1,
                  const float* __restrict__ p2, const float* __restrict__ p3,
                  float* __restrict__ out, int H, int W, int C_out)
{
    constexpr int NP = 324;
    constexpr int CT = COP / 16;
    constexpr int CPB = CT / CSPLIT;             // co-tiles per block
    __shared__ unsigned short xs[8 * NP * 8];

    int tid  = threadIdx.x;
    int lane = tid & 63, wid = tid >> 6;
    int lrow = lane >> 4, lcol = lane & 15;
    int x0 = blockIdx.x * 16, y0 = blockIdx.y * 16;
    int b  = blockIdx.z / CSPLIT;
    int cs = blockIdx.z % CSPLIT;
    int HWp = H * W;
    const float* xb = x + (size_t)b * 64 * HWp;

    unsigned int* wsl = (unsigned int*)xs;
    for (int p = tid; p < NP; p += 256) {
        int py = p / 18, px = p - py * 18;
        int gy = y0 + py - 1, gx = x0 + px - 1;
        bool ok = (gy >= 0) && (gy < H) && (gx >= 0) && (gx < W);
        const float* gp = xb + (size_t)gy * W + gx;
#pragma unroll 8
        for (int cp = 0; cp < 32; ++cp) {
            float v0 = 0.f, v1 = 0.f;
            if (ok) {
                v0 = gp[(size_t)(2 * cp) * HWp];
                v1 = gp[(size_t)(2 * cp + 1) * HWp];
            }
            unsigned pk = ((unsigned)f2bf(v1) << 16) | (unsigned)f2bf(v0);
            wsl[((cp >> 2) * NP + p) * 4 + (cp & 3)] = pk;
        }
    }
    __syncthreads();

    bool colok = (x0 + lcol) < W;

    for (int ct = cs * CPB; ct < (cs + 1) * CPB; ++ct) {
        int co0 = ct * 16;

        bf16x8 a[9][2];
        const unsigned short* wl = wt + ((size_t)co0 + lcol) * 64 + lrow * 8;
#pragma unroll
        for (int t = 0; t < 9; ++t)
#pragma unroll
            for (int kb = 0; kb < 2; ++kb)
                a[t][kb] = *(const bf16x8*)(wl + (size_t)t * COP * 64 + kb * 32);

        float sc[4], sh[4];
#pragma unroll
        for (int rg = 0; rg < 4; ++rg) {
            int co = co0 + lrow * 4 + rg;
            int cc = (co < C_out) ? co : 0;
            if (MODE == 0) { sc[rg] = 1.f; sh[rg] = p0[cc]; }
            else {
                float inv = p0[cc] * rsqrtf(p3[cc] + BN_EPS);
                sc[rg] = inv; sh[rg] = p1[cc] - p2[cc] * inv;
            }
        }

#pragma unroll
        for (int rr = 0; rr < 2; ++rr) {
            int r0 = wid + rr * 8;
            f32x4 acc0 = {0.f, 0.f, 0.f, 0.f};
            f32x4 acc1 = {0.f, 0.f, 0.f, 0.f};
#pragma unroll
            for (int t = 0; t < 9; ++t) {
                int dy = t / 3, dx = t - dy * 3;
#pragma unroll
                for (int kb = 0; kb < 2; ++kb) {
                    int g0 = (kb * 4 + lrow) * NP + (r0 + dy) * 18 + lcol + dx;
                    bf16x8 b0 = *(const bf16x8*)(xs + (size_t)g0 * 8);
                    acc0 = __builtin_amdgcn_mfma_f32_16x16x32_bf16(a[t][kb], b0, acc0, 0, 0, 0);
                    bf16x8 b1 = *(const bf16x8*)(xs + ((size_t)g0 + 4 * 18) * 8);
                    acc1 = __builtin_amdgcn_mfma_f32_16x16x32_bf16(a[t][kb], b1, acc1, 0, 0, 0);
                }
            }
            int yA = y0 + r0, yB = y0 + r0 + 4;
#pragma unroll
            for (int rg = 0; rg < 4; ++rg) {
                int co = co0 + lrow * 4 + rg;
                if (colok && co < C_out) {
                    float* oc = out + (((size_t)b * C_out + co) * H) * W + x0 + lcol;
                    if (yA < H) oc[(size_t)yA * W] = acc0[rg] * sc[rg] + sh[rg];
                    if (yB < H) oc[(size_t)yB * W] = acc1[rg] * sc[rg] + sh[rg];
                }
            }
        }
    }
}

// ---------------------------------------------------------------------------
// conv1x1 v5: bf16 MFMA GEMM (R9 version — known good)
// grid: (HW/NPX, KSPLIT, B), block 256.  Requires HW % NPX == 0.
// ---------------------------------------------------------------------------
template<int C_IN, int KSPLIT, int NPX, int MODE>
__global__ __launch_bounds__(256, 4)
void conv1x1_mfma(const float* __restrict__ x, const unsigned short* __restrict__ wb,
                  const float* __restrict__ p0, const float* __restrict__ p1,
                  const float* __restrict__ p2, const float* __restrict__ p3,
                  float* __restrict__ out, int HW)
{
    constexpr int NT = NPX / 16;
    constexpr int KLEN = C_IN / KSPLIT;
    __shared__ __align__(16) unsigned short xs[4][NPX][8];

    int tid = threadIdx.x;
    int lane = tid & 63, wid = tid >> 6;
    int lrow = lane >> 4, lcol = lane & 15;
    int px0 = blockIdx.x * NPX;
    int ks  = blockIdx.y;
    int b   = blockIdx.z;
    const float* xb = x + (size_t)b * C_IN * HW + px0;

    f32x4 acc[NT];
#pragma unroll
    for (int nt = 0; nt < NT; ++nt) acc[nt] = (f32x4){0.f, 0.f, 0.f, 0.f};

    for (int cc = 0; cc < KLEN; cc += 32) {
        if (cc) __syncthreads();
        int cb = ks * KLEN + cc;
#pragma unroll
        for (int t = 0; t < NPX / 16; ++t) {
            int i = tid + t * 256;
            int px = i & (NPX - 1);
            int cp = i / NPX;
            float v0 = xb[(size_t)(cb + 2 * cp) * HW + px];
            float v1 = xb[(size_t)(cb + 2 * cp + 1) * HW + px];
            unsigned pk = ((unsigned)f2bf(v1) << 16) | (unsigned)f2bf(v0);
            ((unsigned*)&xs[cp >> 2][px][0])[cp & 3] = pk;
        }
        __syncthreads();

        bf16x8 a = *(const bf16x8*)(wb + (size_t)(wid * 16 + lcol) * C_IN + cb + lrow * 8);
#pragma unroll
        for (int nt = 0; nt < NT; ++nt) {
            bf16x8 bf = *(const bf16x8*)&xs[lrow][nt * 16 + lcol][0];
            acc[nt] = __builtin_amdgcn_mfma_f32_16x16x32_bf16(a, bf, acc[nt], 0, 0, 0);
        }
    }

    if (KSPLIT == 1) {
#pragma unroll
        for (int rg = 0; rg < 4; ++rg) {
            int co = wid * 16 + lrow * 4 + rg;
            float scale, shift;
            if (MODE == 0) { scale = 1.f; shift = p0[co]; }
            else {
                float inv = p0[co] * rsqrtf(p3[co] + BN_EPS);
                scale = inv; shift = p1[co] - p2[co] * inv;
            }
            float* op = out + ((size_t)(b * 64 + co)) * HW + px0;
#pragma unroll
            for (int nt = 0; nt < NT; ++nt) {
                float r = acc[nt][rg] * scale + shift;
                if (MODE == 1) r = fmaxf(r, 0.f);
                op[nt * 16 + lcol] = r;
            }
        }
    } else {
#pragma unroll
        for (int rg = 0; rg < 4; ++rg) {
            int co = wid * 16 + lrow * 4 + rg;
            float* op = out + (((size_t)(ks * 4 + b)) * 64 + co) * HW + px0;
#pragma unroll
            for (int nt = 0; nt < NT; ++nt)
                op[nt * 16 + lcol] = acc[nt][rg];
        }
    }
}

// ---------------------------------------------------------------------------
// K-split reduce + bias: out[i] = sum_ks part[ks][i] + bias[co]
// grid: N4/256 blocks (N4 = B*64*HW/4, exact)
// ---------------------------------------------------------------------------
template<int KSPLIT>
__global__ __launch_bounds__(256)
void ksplit_reduce(const float* __restrict__ part, const float* __restrict__ bias,
                   float* __restrict__ out, int HW, int N4)
{
    int i = blockIdx.x * 256 + threadIdx.x;
    if (i >= N4) return;
    size_t base = (size_t)i * 4;
    int co = (int)((base / (size_t)HW) & 63);
    size_t stride = (size_t)HW << 8;
    float4 s = *(const float4*)(part + base);
#pragma unroll
    for (int ks = 1; ks < KSPLIT; ++ks) {
        float4 t = *(const float4*)(part + (size_t)ks * stride + base);
        s.x += t.x; s.y += t.y; s.z += t.z; s.w += t.w;
    }
    float bv = bias[co];
    s.x += bv; s.y += bv; s.z += bv; s.w += bv;
    *(float4*)(out + base) = s;
}

// ---------------------------------------------------------------------------
// CARAFE v3 (R6 version — known good)
// grid: (2w/16, 2h/16, B), block 256
// ---------------------------------------------------------------------------
__global__ __launch_bounds__(256, 4)
void carafe_kernel(const float* __restrict__ src, const float* __restrict__ logits,
                   float* __restrict__ dst, int h, int w)
{
    constexpr int SW = 12, NPX = 144, CS = 68;
    __shared__ float ls[NPX * CS];

    int tid = threadIdx.x;
    int x0 = blockIdx.x * 16, y0 = blockIdx.y * 16;
    int b = blockIdx.z;
    int H = 2 * h, W = 2 * w;
    int xs0 = (x0 >> 1) - 2, ys0 = (y0 >> 1) - 2;
    size_t hw = (size_t)h * w;
    const float* sb = src + (size_t)b * 64 * hw;

    for (int i = tid; i < NPX * 64; i += 256) {
        int c = i / NPX, p = i - c * NPX;
        int yy = p / SW, xx = p - yy * SW;
        int sy = ys0 + yy, sx = xs0 + xx;
        float v = 0.f;
        if (sy >= 0 && sy < h && sx >= 0 && sx < w)
            v = sb[(size_t)c * hw + (size_t)sy * w + sx];
        ls[p * CS + c] = v;
    }
    __syncthreads();

    int lx = tid & 15, ty = tid >> 4;
    int x = x0 + lx, y = y0 + ty;
    int xw = x >> 1, yh = y >> 1;
    int par = (y & 1) * 2 + (x & 1);

    const float* lp = logits + ((size_t)(b * 100 + par) * h + yh) * w + xw;
    float l[25];
    float mx = -1e30f;
#pragma unroll
    for (int k = 0; k < 25; ++k) {
        l[k] = lp[(size_t)(4 * k) * hw];
        mx = fmaxf(mx, l[k]);
    }
    float s = 0.f;
#pragma unroll
    for (int k = 0; k < 25; ++k) {
        l[k] = __expf(l[k] - mx);
        s += l[k];
    }
    float invs = 1.f / s;
#pragma unroll
    for (int k = 0; k < 25; ++k) l[k] *= invs;

    int pb = (yh - ys0 - 2) * SW + (xw - xs0 - 2);

#pragma unroll 1
    for (int cg = 0; cg < 4; ++cg) {
        float acc[16];
#pragma unroll
        for (int c = 0; c < 16; ++c) acc[c] = 0.f;
#pragma unroll
        for (int k = 0; k < 25; ++k) {
            int ti = k / 5, tj = k - ti * 5;
            const float* q = &ls[(pb + ti * SW + tj) * CS + cg * 16];
            float wk = l[k];
#pragma unroll
            for (int c = 0; c < 16; ++c)
                acc[c] = fmaf(wk, q[c], acc[c]);
        }
        float* dp = dst + (((size_t)(b * 64 + cg * 16)) * H + y) * W + x;
#pragma unroll
        for (int c = 0; c < 16; ++c)
            dp[(size_t)c * H * W] += acc[c];
    }
}

// ---------------------------------------------------------------------------
extern "C" void kernel_launch(void* const* d_in, const int* in_sizes, int n_in,
                              void* d_out, int out_size, void* d_ws, size_t ws_size,
                              hipStream_t stream)
{
    const float* x0      = (const float*)d_in[0];
    const float* lat0_w  = (const float*)d_in[1];
    const float* lat0_b  = (const float*)d_in[2];
    const float* fpn0_w  = (const float*)d_in[3];
    const float* fpn0_b  = (const float*)d_in[4];
    const float* x1      = (const float*)d_in[5];
    const float* lat1_w  = (const float*)d_in[6];
    const float* lat1_b  = (const float*)d_in[7];
    const float* fpn1_w  = (const float*)d_in[8];
    const float* fpn1_b  = (const float*)d_in[9];
    const float* x2      = (const float*)d_in[10];
    const float* lat2_w  = (const float*)d_in[11];
    const float* lat2_b  = (const float*)d_in[12];
    const float* fpn2_w  = (const float*)d_in[13];
    const float* fpn2_b  = (const float*)d_in[14];
    const float* u0_comp_w = (const float*)d_in[15];
    const float* u0_enc_w  = (const float*)d_in[16];
    const float* u0_comp_g  = (const float*)d_in[17];
    const float* u0_comp_bt = (const float*)d_in[18];
    const float* u0_comp_m  = (const float*)d_in[19];
    const float* u0_comp_v  = (const float*)d_in[20];
    const float* u0_enc_g   = (const float*)d_in[21];
    const float* u0_enc_bt  = (const float*)d_in[22];
    const float* u0_enc_m   = (const float*)d_in[23];
    const float* u0_enc_v   = (const float*)d_in[24];
    const float* u1_comp_w = (const float*)d_in[25];
    const float* u1_enc_w  = (const float*)d_in[26];
    const float* u1_comp_g  = (const float*)d_in[27];
    const float* u1_comp_bt = (const float*)d_in[28];
    const float* u1_comp_m  = (const float*)d_in[29];
    const float* u1_comp_v  = (const float*)d_in[30];
    const float* u1_enc_g   = (const float*)d_in[31];
    const float* u1_enc_bt  = (const float*)d_in[32];
    const float* u1_enc_m   = (const float*)d_in[33];
    const float* u1_enc_v   = (const float*)d_in[34];

    float* out = (float*)d_out;
    const size_t OUT0 = 4ull * 64 * 96 * 160;   // 3,932,160
    const size_t OUT1 = 4ull * 64 * 48 * 80;    //   983,040
    const size_t OUT2 = 4ull * 64 * 24 * 40;    //   245,760
    float* out0 = out;
    float* out1 = out + OUT0;
    float* out2 = out + OUT0 + OUT1;

    float* lat0 = (float*)d_ws;
    float* lat1 = lat0 + OUT0;
    float* lat2 = lat1 + OUT1;
    unsigned short* wtb = (unsigned short*)(lat2 + OUT2);   // 239,616 bf16
    unsigned short* wt_fpn0 = wtb;
    unsigned short* wt_fpn1 = wtb + 36864;
    unsigned short* wt_fpn2 = wtb + 73728;
    unsigned short* wt_enc0 = wtb + 110592;
    unsigned short* wt_enc1 = wtb + 175104;
    unsigned short* wb = wtb + 239616;                      // 65,536 bf16 (1x1)
    unsigned short* wb_lat0  = wb;
    unsigned short* wb_lat1  = wb + 8192;
    unsigned short* wb_lat2  = wb + 24576;
    unsigned short* wb_comp0 = wb + 57344;
    unsigned short* wb_comp1 = wb + 61440;
    // out0 region doubles as scratch (overwritten last by fpn0 conv):
    float* part = out0;          // K-split partials (stage 1 only)
    float* comp = out0;          // comp logits (stages 2-3)
    float* enc  = out0 + OUT1;   // enc logits

    dim3 blk(256);

    // 0) weight prep
    prep_weights<<<dim3(252, 10), blk, 0, stream>>>(
        fpn0_w, fpn1_w, fpn2_w, u0_enc_w, u1_enc_w, wtb,
        lat0_w, lat1_w, lat2_w, u0_comp_w, u1_comp_w, wb);

    // 1) lateral 1x1 convs + bias (MFMA)
    conv1x1_mfma<128, 1, 128, 0><<<dim3(120, 1, 4), blk, 0, stream>>>(
        x0, wb_lat0, lat0_b, nullptr, nullptr, nullptr, lat0, 96 * 160);
    conv1x1_mfma<256, 2, 128, 0><<<dim3(30, 2, 4), blk, 0, stream>>>(
        x1, wb_lat1, nullptr, nullptr, nullptr, nullptr, part, 48 * 80);
    ksplit_reduce<2><<<dim3(960), blk, 0, stream>>>(part, lat1_b, lat1, 48 * 80, 245760);
    conv1x1_mfma<512, 4, 64, 0><<<dim3(15, 4, 4), blk, 0, stream>>>(
        x2, wb_lat2, nullptr, nullptr, nullptr, nullptr, part, 24 * 40);
    ksplit_reduce<4><<<dim3(240), blk, 0, stream>>>(part, lat2_b, lat2, 24 * 40, 61440);

    // 2) CARAFE u1: lat1 += carafe(lat2)
    conv1x1_mfma<64, 1, 64, 1><<<dim3(15, 1, 4), blk, 0, stream>>>(
        lat2, wb_comp1, u1_comp_g, u1_comp_bt, u1_comp_m, u1_comp_v, comp, 24 * 40);
    conv3x3_mfma<112, 7, 1><<<dim3(3, 2, 28), blk, 0, stream>>>(
        comp, wt_enc1, u1_enc_g, u1_enc_bt, u1_enc_m, u1_enc_v, enc, 24, 40, 100);
    carafe_kernel<<<dim3(5, 3, 4), blk, 0, stream>>>(lat2, enc, lat1, 24, 40);

    // 3) CARAFE u0: lat0 += carafe(lat1)
    conv1x1_mfma<64, 1, 128, 1><<<dim3(30, 1, 4), blk, 0, stream>>>(
        lat1, wb_comp0, u0_comp_g, u0_comp_bt, u0_comp_m, u0_comp_v, comp, 48 * 80);
    conv3x3_mfma<112, 7, 1><<<dim3(5, 3, 28), blk, 0, stream>>>(
        comp, wt_enc0, u0_enc_g, u0_enc_bt, u0_enc_m, u0_enc_v, enc, 48, 80, 100);
    carafe_kernel<<<dim3(10, 6, 4), blk, 0, stream>>>(lat1, enc, lat0, 48, 80);

    // 4) output 3x3 convs + bias  (fpn0 LAST — its region held scratch)
    conv3x3_mfma<64, 4, 0><<<dim3(5, 3, 16), blk, 0, stream>>>(
        lat1, wt_fpn1, fpn1_b, nullptr, nullptr, nullptr, out1, 48, 80, 64);
    conv3x3_mfma<64, 4, 0><<<dim3(3, 2, 16), blk, 0, stream>>>(
        lat2, wt_fpn2, fpn2_b, nullptr, nullptr, nullptr, out2, 24, 40, 64);
    conv3x3_mfma<64, 2, 0><<<dim3(10, 6, 8), blk, 0, stream>>>(
        lat0, wt_fpn0, fpn0_b, nullptr, nullptr, nullptr, out0, 96, 160, 64);
}

// Round 12
// 417.065 us; speedup vs baseline: 1.4738x; 1.0452x over previous
//
#include <hip/hip_runtime.h>

#define BN_EPS 1e-5f

typedef __attribute__((ext_vector_type(8))) short bf16x8;
typedef __attribute__((ext_vector_type(4))) float f32x4;

__device__ __forceinline__ unsigned short f2bf(float f) {
    unsigned u = __float_as_uint(f);
    return (unsigned short)((u + 0x7fffu + ((u >> 16) & 1u)) >> 16);   // RNE
}

// ---------------------------------------------------------------------------
// Weight prep (ONE launch):
// z 0..2: fpn0/1/2 conv3x3 -> wt[tap][co64][ci] bf16
// z 3..4: enc0/1  conv3x3 -> wt[tap][co112][ci] bf16 (zero-pad co 100->112)
// z 5..9: lat0/lat1/lat2/comp0/comp1 1x1 -> straight bf16 cast [co][ci]
// grid (252, 10), block 256
// ---------------------------------------------------------------------------
__global__ __launch_bounds__(256)
void prep_weights(const float* __restrict__ w0, const float* __restrict__ w1,
                  const float* __restrict__ w2, const float* __restrict__ w3,
                  const float* __restrict__ w4, unsigned short* __restrict__ dst,
                  const float* __restrict__ v0, const float* __restrict__ v1,
                  const float* __restrict__ v2, const float* __restrict__ v3,
                  const float* __restrict__ v4, unsigned short* __restrict__ dst1)
{
    int z = blockIdx.y;
    int i = blockIdx.x * 256 + threadIdx.x;
    if (z < 5) {
        const float* src; unsigned short* d; int C_out, COP;
        if (z < 3) {
            COP = 64; C_out = 64;
            src = (z == 0) ? w0 : (z == 1 ? w1 : w2);
            d = dst + z * 36864;
            if (i >= 36864) return;
        } else {
            COP = 112; C_out = 100;
            src = (z == 3) ? w3 : w4;
            d = dst + 110592 + (z - 3) * 64512;
            if (i >= 64512) return;
        }
        int tap = i / (COP * 64);
        int rem = i - tap * (COP * 64);
        int co = rem >> 6, ci = rem & 63;
        float v = (co < C_out) ? src[((size_t)co * 64 + ci) * 9 + tap] : 0.f;
        d[i] = f2bf(v);
    } else {
        int zz = z - 5;
        const float* s; int n; int off;
        if (zz == 0)      { s = v0; n = 8192;  off = 0; }
        else if (zz == 1) { s = v1; n = 16384; off = 8192; }
        else if (zz == 2) { s = v2; n = 32768; off = 24576; }
        else if (zz == 3) { s = v3; n = 4096;  off = 57344; }
        else              { s = v4; n = 4096;  off = 61440; }
        if (i >= n) return;
        dst1[off + i] = f2bf(s[i]);
    }
}

// ---------------------------------------------------------------------------
// conv3x3 via bf16 MFMA (16x16x32), pad=1, C_in=64, fp32 accumulate.
// CSPLIT co-tile split across blocks (R11: fixed enc0 starvation).
// grid: (ceil(W/16), ceil(H/16), B * CSPLIT), block 256
// ---------------------------------------------------------------------------
template<int COP, int CSPLIT, int MODE>
__global__ __launch_bounds__(256, 4)
void conv3x3_mfma(const float* __restrict__ x, const unsigned short* __restrict__ wt,
                  const float* __restrict__ p0, const float* __restrict__ p1,
                  const float* __restrict__ p2, const float* __restrict__ p3,
                  float* __restrict__ out, int H, int W, int C_out)
{
    constexpr int NP = 324;
    constexpr int CT = COP / 16;
    constexpr int CPB = CT / CSPLIT;
    __shared__ unsigned short xs[8 * NP * 8];

    int tid  = threadIdx.x;
    int lane = tid & 63, wid = tid >> 6;
    int lrow = lane >> 4, lcol = lane & 15;
    int x0 = blockIdx.x * 16, y0 = blockIdx.y * 16;
    int b  = blockIdx.z / CSPLIT;
    int cs = blockIdx.z % CSPLIT;
    int HWp = H * W;
    const float* xb = x + (size_t)b * 64 * HWp;

    unsigned int* wsl = (unsigned int*)xs;
    for (int p = tid; p < NP; p += 256) {
        int py = p / 18, px = p - py * 18;
        int gy = y0 + py - 1, gx = x0 + px - 1;
        bool ok = (gy >= 0) && (gy < H) && (gx >= 0) && (gx < W);
        const float* gp = xb + (size_t)gy * W + gx;
#pragma unroll 8
        for (int cp = 0; cp < 32; ++cp) {
            float v0 = 0.f, v1 = 0.f;
            if (ok) {
                v0 = gp[(size_t)(2 * cp) * HWp];
                v1 = gp[(size_t)(2 * cp + 1) * HWp];
            }
            unsigned pk = ((unsigned)f2bf(v1) << 16) | (unsigned)f2bf(v0);
            wsl[((cp >> 2) * NP + p) * 4 + (cp & 3)] = pk;
        }
    }
    __syncthreads();

    bool colok = (x0 + lcol) < W;

    for (int ct = cs * CPB; ct < (cs + 1) * CPB; ++ct) {
        int co0 = ct * 16;

        bf16x8 a[9][2];
        const unsigned short* wl = wt + ((size_t)co0 + lcol) * 64 + lrow * 8;
#pragma unroll
        for (int t = 0; t < 9; ++t)
#pragma unroll
            for (int kb = 0; kb < 2; ++kb)
                a[t][kb] = *(const bf16x8*)(wl + (size_t)t * COP * 64 + kb * 32);

        float sc[4], sh[4];
#pragma unroll
        for (int rg = 0; rg < 4; ++rg) {
            int co = co0 + lrow * 4 + rg;
            int cc = (co < C_out) ? co : 0;
            if (MODE == 0) { sc[rg] = 1.f; sh[rg] = p0[cc]; }
            else {
                float inv = p0[cc] * rsqrtf(p3[cc] + BN_EPS);
                sc[rg] = inv; sh[rg] = p1[cc] - p2[cc] * inv;
            }
        }

#pragma unroll
        for (int rr = 0; rr < 2; ++rr) {
            int r0 = wid + rr * 8;
            f32x4 acc0 = {0.f, 0.f, 0.f, 0.f};
            f32x4 acc1 = {0.f, 0.f, 0.f, 0.f};
#pragma unroll
            for (int t = 0; t < 9; ++t) {
                int dy = t / 3, dx = t - dy * 3;
#pragma unroll
                for (int kb = 0; kb < 2; ++kb) {
                    int g0 = (kb * 4 + lrow) * NP + (r0 + dy) * 18 + lcol + dx;
                    bf16x8 b0 = *(const bf16x8*)(xs + (size_t)g0 * 8);
                    acc0 = __builtin_amdgcn_mfma_f32_16x16x32_bf16(a[t][kb], b0, acc0, 0, 0, 0);
                    bf16x8 b1 = *(const bf16x8*)(xs + ((size_t)g0 + 4 * 18) * 8);
                    acc1 = __builtin_amdgcn_mfma_f32_16x16x32_bf16(a[t][kb], b1, acc1, 0, 0, 0);
                }
            }
            int yA = y0 + r0, yB = y0 + r0 + 4;
#pragma unroll
            for (int rg = 0; rg < 4; ++rg) {
                int co = co0 + lrow * 4 + rg;
                if (colok && co < C_out) {
                    float* oc = out + (((size_t)b * C_out + co) * H) * W + x0 + lcol;
                    if (yA < H) oc[(size_t)yA * W] = acc0[rg] * sc[rg] + sh[rg];
                    if (yB < H) oc[(size_t)yB * W] = acc1[rg] * sc[rg] + sh[rg];
                }
            }
        }
    }
}

// ---------------------------------------------------------------------------
// conv1x1 v5: bf16 MFMA GEMM (R9 version — known good)
// grid: (HW/NPX, KSPLIT, B), block 256.  Requires HW % NPX == 0.
// ---------------------------------------------------------------------------
template<int C_IN, int KSPLIT, int NPX, int MODE>
__global__ __launch_bounds__(256, 4)
void conv1x1_mfma(const float* __restrict__ x, const unsigned short* __restrict__ wb,
                  const float* __restrict__ p0, const float* __restrict__ p1,
                  const float* __restrict__ p2, const float* __restrict__ p3,
                  float* __restrict__ out, int HW)
{
    constexpr int NT = NPX / 16;
    constexpr int KLEN = C_IN / KSPLIT;
    __shared__ __align__(16) unsigned short xs[4][NPX][8];

    int tid = threadIdx.x;
    int lane = tid & 63, wid = tid >> 6;
    int lrow = lane >> 4, lcol = lane & 15;
    int px0 = blockIdx.x * NPX;
    int ks  = blockIdx.y;
    int b   = blockIdx.z;
    const float* xb = x + (size_t)b * C_IN * HW + px0;

    f32x4 acc[NT];
#pragma unroll
    for (int nt = 0; nt < NT; ++nt) acc[nt] = (f32x4){0.f, 0.f, 0.f, 0.f};

    for (int cc = 0; cc < KLEN; cc += 32) {
        if (cc) __syncthreads();
        int cb = ks * KLEN + cc;
#pragma unroll
        for (int t = 0; t < NPX / 16; ++t) {
            int i = tid + t * 256;
            int px = i & (NPX - 1);
            int cp = i / NPX;
            float v0 = xb[(size_t)(cb + 2 * cp) * HW + px];
            float v1 = xb[(size_t)(cb + 2 * cp + 1) * HW + px];
            unsigned pk = ((unsigned)f2bf(v1) << 16) | (unsigned)f2bf(v0);
            ((unsigned*)&xs[cp >> 2][px][0])[cp & 3] = pk;
        }
        __syncthreads();

        bf16x8 a = *(const bf16x8*)(wb + (size_t)(wid * 16 + lcol) * C_IN + cb + lrow * 8);
#pragma unroll
        for (int nt = 0; nt < NT; ++nt) {
            bf16x8 bf = *(const bf16x8*)&xs[lrow][nt * 16 + lcol][0];
            acc[nt] = __builtin_amdgcn_mfma_f32_16x16x32_bf16(a, bf, acc[nt], 0, 0, 0);
        }
    }

    if (KSPLIT == 1) {
#pragma unroll
        for (int rg = 0; rg < 4; ++rg) {
            int co = wid * 16 + lrow * 4 + rg;
            float scale, shift;
            if (MODE == 0) { scale = 1.f; shift = p0[co]; }
            else {
                float inv = p0[co] * rsqrtf(p3[co] + BN_EPS);
                scale = inv; shift = p1[co] - p2[co] * inv;
            }
            float* op = out + ((size_t)(b * 64 + co)) * HW + px0;
#pragma unroll
            for (int nt = 0; nt < NT; ++nt) {
                float r = acc[nt][rg] * scale + shift;
                if (MODE == 1) r = fmaxf(r, 0.f);
                op[nt * 16 + lcol] = r;
            }
        }
    } else {
#pragma unroll
        for (int rg = 0; rg < 4; ++rg) {
            int co = wid * 16 + lrow * 4 + rg;
            float* op = out + (((size_t)(ks * 4 + b)) * 64 + co) * HW + px0;
#pragma unroll
            for (int nt = 0; nt < NT; ++nt)
                op[nt * 16 + lcol] = acc[nt][rg];
        }
    }
}

// ---------------------------------------------------------------------------
// K-split reduce + bias: out[i] = sum_ks part[ks][i] + bias[co]
// grid: N4/256 blocks (N4 = B*64*HW/4, exact)
// ---------------------------------------------------------------------------
template<int KSPLIT>
__global__ __launch_bounds__(256)
void ksplit_reduce(const float* __restrict__ part, const float* __restrict__ bias,
                   float* __restrict__ out, int HW, int N4)
{
    int i = blockIdx.x * 256 + threadIdx.x;
    if (i >= N4) return;
    size_t base = (size_t)i * 4;
    int co = (int)((base / (size_t)HW) & 63);
    size_t stride = (size_t)HW << 8;
    float4 s = *(const float4*)(part + base);
#pragma unroll
    for (int ks = 1; ks < KSPLIT; ++ks) {
        float4 t = *(const float4*)(part + (size_t)ks * stride + base);
        s.x += t.x; s.y += t.y; s.z += t.z; s.w += t.w;
    }
    float bv = bias[co];
    s.x += bv; s.y += bv; s.z += bv; s.w += bv;
    *(float4*)(out + base) = s;
}

// ---------------------------------------------------------------------------
// CARAFE v4: channel-group split. R11 showed u0 at 240 blocks / 8% occupancy
// / 45.7us — block starvation (traffic floor is ~7us). CGS=2: each block
// stages 32 channels (LDS 39.4->20.7 KB, 7 blocks/CU) -> 2x blocks. Cost:
// logits re-read + softmax recompute per half (VALU/HBM both idle = free).
// grid: (2w/16, 2h/16, B * CGS), block 256
// ---------------------------------------------------------------------------
template<int CGS>
__global__ __launch_bounds__(256, 4)
void carafe_kernel(const float* __restrict__ src, const float* __restrict__ logits,
                   float* __restrict__ dst, int h, int w)
{
    constexpr int SW = 12, NPX = 144;
    constexpr int CH = 64 / CGS;                 // channels per block
    constexpr int CS = CH + 4;                   // LDS channel stride
    __shared__ float ls[NPX * CS];

    int tid = threadIdx.x;
    int x0 = blockIdx.x * 16, y0 = blockIdx.y * 16;
    int b  = blockIdx.z / CGS;
    int cs = blockIdx.z % CGS;
    int H = 2 * h, W = 2 * w;
    int xs0 = (x0 >> 1) - 2, ys0 = (y0 >> 1) - 2;
    size_t hw = (size_t)h * w;
    const float* sb = src + ((size_t)(b * 64 + cs * CH)) * hw;

    for (int i = tid; i < NPX * CH; i += 256) {
        int c = i / NPX, p = i - c * NPX;
        int yy = p / SW, xx = p - yy * SW;
        int sy = ys0 + yy, sx = xs0 + xx;
        float v = 0.f;
        if (sy >= 0 && sy < h && sx >= 0 && sx < w)
            v = sb[(size_t)c * hw + (size_t)sy * w + sx];
        ls[p * CS + c] = v;
    }
    __syncthreads();

    int lx = tid & 15, ty = tid >> 4;
    int x = x0 + lx, y = y0 + ty;
    int xw = x >> 1, yh = y >> 1;
    int par = (y & 1) * 2 + (x & 1);

    const float* lp = logits + ((size_t)(b * 100 + par) * h + yh) * w + xw;
    float l[25];
    float mx = -1e30f;
#pragma unroll
    for (int k = 0; k < 25; ++k) {
        l[k] = lp[(size_t)(4 * k) * hw];
        mx = fmaxf(mx, l[k]);
    }
    float s = 0.f;
#pragma unroll
    for (int k = 0; k < 25; ++k) {
        l[k] = __expf(l[k] - mx);
        s += l[k];
    }
    float invs = 1.f / s;
#pragma unroll
    for (int k = 0; k < 25; ++k) l[k] *= invs;

    int pb = (yh - ys0 - 2) * SW + (xw - xs0 - 2);

#pragma unroll 1
    for (int cg = 0; cg < CH / 16; ++cg) {
        float acc[16];
#pragma unroll
        for (int c = 0; c < 16; ++c) acc[c] = 0.f;
#pragma unroll
        for (int k = 0; k < 25; ++k) {
            int ti = k / 5, tj = k - ti * 5;
            const float* q = &ls[(pb + ti * SW + tj) * CS + cg * 16];
            float wk = l[k];
#pragma unroll
            for (int c = 0; c < 16; ++c)
                acc[c] = fmaf(wk, q[c], acc[c]);
        }
        float* dp = dst + (((size_t)(b * 64 + cs * CH + cg * 16)) * H + y) * W + x;
#pragma unroll
        for (int c = 0; c < 16; ++c)
            dp[(size_t)c * H * W] += acc[c];
    }
}

// ---------------------------------------------------------------------------
extern "C" void kernel_launch(void* const* d_in, const int* in_sizes, int n_in,
                              void* d_out, int out_size, void* d_ws, size_t ws_size,
                              hipStream_t stream)
{
    const float* x0      = (const float*)d_in[0];
    const float* lat0_w  = (const float*)d_in[1];
    const float* lat0_b  = (const float*)d_in[2];
    const float* fpn0_w  = (const float*)d_in[3];
    const float* fpn0_b  = (const float*)d_in[4];
    const float* x1      = (const float*)d_in[5];
    const float* lat1_w  = (const float*)d_in[6];
    const float* lat1_b  = (const float*)d_in[7];
    const float* fpn1_w  = (const float*)d_in[8];
    const float* fpn1_b  = (const float*)d_in[9];
    const float* x2      = (const float*)d_in[10];
    const float* lat2_w  = (const float*)d_in[11];
    const float* lat2_b  = (const float*)d_in[12];
    const float* fpn2_w  = (const float*)d_in[13];
    const float* fpn2_b  = (const float*)d_in[14];
    const float* u0_comp_w = (const float*)d_in[15];
    const float* u0_enc_w  = (const float*)d_in[16];
    const float* u0_comp_g  = (const float*)d_in[17];
    const float* u0_comp_bt = (const float*)d_in[18];
    const float* u0_comp_m  = (const float*)d_in[19];
    const float* u0_comp_v  = (const float*)d_in[20];
    const float* u0_enc_g   = (const float*)d_in[21];
    const float* u0_enc_bt  = (const float*)d_in[22];
    const float* u0_enc_m   = (const float*)d_in[23];
    const float* u0_enc_v   = (const float*)d_in[24];
    const float* u1_comp_w = (const float*)d_in[25];
    const float* u1_enc_w  = (const float*)d_in[26];
    const float* u1_comp_g  = (const float*)d_in[27];
    const float* u1_comp_bt = (const float*)d_in[28];
    const float* u1_comp_m  = (const float*)d_in[29];
    const float* u1_comp_v  = (const float*)d_in[30];
    const float* u1_enc_g   = (const float*)d_in[31];
    const float* u1_enc_bt  = (const float*)d_in[32];
    const float* u1_enc_m   = (const float*)d_in[33];
    const float* u1_enc_v   = (const float*)d_in[34];

    float* out = (float*)d_out;
    const size_t OUT0 = 4ull * 64 * 96 * 160;   // 3,932,160
    const size_t OUT1 = 4ull * 64 * 48 * 80;    //   983,040
    const size_t OUT2 = 4ull * 64 * 24 * 40;    //   245,760
    float* out0 = out;
    float* out1 = out + OUT0;
    float* out2 = out + OUT0 + OUT1;

    float* lat0 = (float*)d_ws;
    float* lat1 = lat0 + OUT0;
    float* lat2 = lat1 + OUT1;
    unsigned short* wtb = (unsigned short*)(lat2 + OUT2);   // 239,616 bf16
    unsigned short* wt_fpn0 = wtb;
    unsigned short* wt_fpn1 = wtb + 36864;
    unsigned short* wt_fpn2 = wtb + 73728;
    unsigned short* wt_enc0 = wtb + 110592;
    unsigned short* wt_enc1 = wtb + 175104;
    unsigned short* wb = wtb + 239616;                      // 65,536 bf16 (1x1)
    unsigned short* wb_lat0  = wb;
    unsigned short* wb_lat1  = wb + 8192;
    unsigned short* wb_lat2  = wb + 24576;
    unsigned short* wb_comp0 = wb + 57344;
    unsigned short* wb_comp1 = wb + 61440;
    // out0 region doubles as scratch (overwritten last by fpn0 conv):
    float* part = out0;          // K-split partials (stage 1 only)
    float* comp = out0;          // comp logits (stages 2-3)
    float* enc  = out0 + OUT1;   // enc logits

    dim3 blk(256);

    // 0) weight prep
    prep_weights<<<dim3(252, 10), blk, 0, stream>>>(
        fpn0_w, fpn1_w, fpn2_w, u0_enc_w, u1_enc_w, wtb,
        lat0_w, lat1_w, lat2_w, u0_comp_w, u1_comp_w, wb);

    // 1) lateral 1x1 convs + bias (MFMA)
    conv1x1_mfma<128, 1, 128, 0><<<dim3(120, 1, 4), blk, 0, stream>>>(
        x0, wb_lat0, lat0_b, nullptr, nullptr, nullptr, lat0, 96 * 160);
    conv1x1_mfma<256, 2, 128, 0><<<dim3(30, 2, 4), blk, 0, stream>>>(
        x1, wb_lat1, nullptr, nullptr, nullptr, nullptr, part, 48 * 80);
    ksplit_reduce<2><<<dim3(960), blk, 0, stream>>>(part, lat1_b, lat1, 48 * 80, 245760);
    conv1x1_mfma<512, 4, 64, 0><<<dim3(15, 4, 4), blk, 0, stream>>>(
        x2, wb_lat2, nullptr, nullptr, nullptr, nullptr, part, 24 * 40);
    ksplit_reduce<4><<<dim3(240), blk, 0, stream>>>(part, lat2_b, lat2, 24 * 40, 61440);

    // 2) CARAFE u1: lat1 += carafe(lat2)
    conv1x1_mfma<64, 1, 32, 1><<<dim3(30, 1, 4), blk, 0, stream>>>(
        lat2, wb_comp1, u1_comp_g, u1_comp_bt, u1_comp_m, u1_comp_v, comp, 24 * 40);
    conv3x3_mfma<112, 7, 1><<<dim3(3, 2, 28), blk, 0, stream>>>(
        comp, wt_enc1, u1_enc_g, u1_enc_bt, u1_enc_m, u1_enc_v, enc, 24, 40, 100);
    carafe_kernel<2><<<dim3(5, 3, 8), blk, 0, stream>>>(lat2, enc, lat1, 24, 40);

    // 3) CARAFE u0: lat0 += carafe(lat1)
    conv1x1_mfma<64, 1, 128, 1><<<dim3(30, 1, 4), blk, 0, stream>>>(
        lat1, wb_comp0, u0_comp_g, u0_comp_bt, u0_comp_m, u0_comp_v, comp, 48 * 80);
    conv3x3_mfma<112, 7, 1><<<dim3(5, 3, 28), blk, 0, stream>>>(
        comp, wt_enc0, u0_enc_g, u0_enc_bt, u0_enc_m, u0_enc_v, enc, 48, 80, 100);
    carafe_kernel<2><<<dim3(10, 6, 8), blk, 0, stream>>>(lat1, enc, lat0, 48, 80);

    // 4) output 3x3 convs + bias  (fpn0 LAST — its region held scratch)
    conv3x3_mfma<64, 4, 0><<<dim3(5, 3, 16), blk, 0, stream>>>(
        lat1, wt_fpn1, fpn1_b, nullptr, nullptr, nullptr, out1, 48, 80, 64);
    conv3x3_mfma<64, 4, 0><<<dim3(3, 2, 16), blk, 0, stream>>>(
        lat2, wt_fpn2, fpn2_b, nullptr, nullptr, nullptr, out2, 24, 40, 64);
    conv3x3_mfma<64, 2, 0><<<dim3(10, 6, 8), blk, 0, stream>>>(
        lat0, wt_fpn0, fpn0_b, nullptr, nullptr, nullptr, out0, 96, 160, 64);
}

// Round 13
// 388.115 us; speedup vs baseline: 1.5837x; 1.0746x over previous
//
#include <hip/hip_runtime.h>

#define BN_EPS 1e-5f

typedef __attribute__((ext_vector_type(8))) short bf16x8;
typedef __attribute__((ext_vector_type(4))) float f32x4;

__device__ __forceinline__ unsigned short f2bf(float f) {
    unsigned u = __float_as_uint(f);
    return (unsigned short)((u + 0x7fffu + ((u >> 16) & 1u)) >> 16);   // RNE
}

// ---------------------------------------------------------------------------
// Weight prep (ONE launch): conv3x3 -> wt[tap][co][ci] bf16; 1x1 -> bf16 cast
// grid (252, 10), block 256
// ---------------------------------------------------------------------------
__global__ __launch_bounds__(256)
void prep_weights(const float* __restrict__ w0, const float* __restrict__ w1,
                  const float* __restrict__ w2, const float* __restrict__ w3,
                  const float* __restrict__ w4, unsigned short* __restrict__ dst,
                  const float* __restrict__ v0, const float* __restrict__ v1,
                  const float* __restrict__ v2, const float* __restrict__ v3,
                  const float* __restrict__ v4, unsigned short* __restrict__ dst1)
{
    int z = blockIdx.y;
    int i = blockIdx.x * 256 + threadIdx.x;
    if (z < 5) {
        const float* src; unsigned short* d; int C_out, COP;
        if (z < 3) {
            COP = 64; C_out = 64;
            src = (z == 0) ? w0 : (z == 1 ? w1 : w2);
            d = dst + z * 36864;
            if (i >= 36864) return;
        } else {
            COP = 112; C_out = 100;
            src = (z == 3) ? w3 : w4;
            d = dst + 110592 + (z - 3) * 64512;
            if (i >= 64512) return;
        }
        int tap = i / (COP * 64);
        int rem = i - tap * (COP * 64);
        int co = rem >> 6, ci = rem & 63;
        float v = (co < C_out) ? src[((size_t)co * 64 + ci) * 9 + tap] : 0.f;
        d[i] = f2bf(v);
    } else {
        int zz = z - 5;
        const float* s; int n; int off;
        if (zz == 0)      { s = v0; n = 8192;  off = 0; }
        else if (zz == 1) { s = v1; n = 16384; off = 8192; }
        else if (zz == 2) { s = v2; n = 32768; off = 24576; }
        else if (zz == 3) { s = v3; n = 4096;  off = 57344; }
        else              { s = v4; n = 4096;  off = 61440; }
        if (i >= n) return;
        dst1[off + i] = f2bf(s[i]);
    }
}

// ---------------------------------------------------------------------------
// conv3x3 body (bf16 MFMA 16x16x32, C_in=64, fp32 acc) — shared by the
// standalone enc kernel and the fused fpn kernel.  xs = 41472 B LDS.
// ---------------------------------------------------------------------------
template<int COP, int CSPLIT, int MODE>
__device__ __forceinline__
void conv3x3_body(int rem, int TX, unsigned short* xs,
                  const float* __restrict__ x, const unsigned short* __restrict__ wt,
                  const float* __restrict__ p0, const float* __restrict__ p1,
                  const float* __restrict__ p2, const float* __restrict__ p3,
                  float* __restrict__ out, int H, int W, int C_out)
{
    constexpr int NP = 324;
    constexpr int CT = COP / 16;
    constexpr int CPB = CT / CSPLIT;

    int cs = rem % CSPLIT;
    int b  = (rem / CSPLIT) & 3;
    int t  = rem / (CSPLIT * 4);
    int x0 = (t % TX) * 16, y0 = (t / TX) * 16;

    int tid  = threadIdx.x;
    int lane = tid & 63, wid = tid >> 6;
    int lrow = lane >> 4, lcol = lane & 15;
    int HWp = H * W;
    const float* xb = x + (size_t)b * 64 * HWp;

    unsigned int* wsl = (unsigned int*)xs;
    for (int p = tid; p < NP; p += 256) {
        int py = p / 18, px = p - py * 18;
        int gy = y0 + py - 1, gx = x0 + px - 1;
        bool ok = (gy >= 0) && (gy < H) && (gx >= 0) && (gx < W);
        const float* gp = xb + (size_t)gy * W + gx;
#pragma unroll 8
        for (int cp = 0; cp < 32; ++cp) {
            float v0 = 0.f, v1 = 0.f;
            if (ok) {
                v0 = gp[(size_t)(2 * cp) * HWp];
                v1 = gp[(size_t)(2 * cp + 1) * HWp];
            }
            unsigned pk = ((unsigned)f2bf(v1) << 16) | (unsigned)f2bf(v0);
            wsl[((cp >> 2) * NP + p) * 4 + (cp & 3)] = pk;
        }
    }
    __syncthreads();

    bool colok = (x0 + lcol) < W;

    for (int ct = cs * CPB; ct < (cs + 1) * CPB; ++ct) {
        int co0 = ct * 16;

        bf16x8 a[9][2];
        const unsigned short* wl = wt + ((size_t)co0 + lcol) * 64 + lrow * 8;
#pragma unroll
        for (int t9 = 0; t9 < 9; ++t9)
#pragma unroll
            for (int kb = 0; kb < 2; ++kb)
                a[t9][kb] = *(const bf16x8*)(wl + (size_t)t9 * COP * 64 + kb * 32);

        float sc[4], sh[4];
#pragma unroll
        for (int rg = 0; rg < 4; ++rg) {
            int co = co0 + lrow * 4 + rg;
            int cc = (co < C_out) ? co : 0;
            if (MODE == 0) { sc[rg] = 1.f; sh[rg] = p0[cc]; }
            else {
                float inv = p0[cc] * rsqrtf(p3[cc] + BN_EPS);
                sc[rg] = inv; sh[rg] = p1[cc] - p2[cc] * inv;
            }
        }

#pragma unroll
        for (int rr = 0; rr < 2; ++rr) {
            int r0 = wid + rr * 8;
            f32x4 acc0 = {0.f, 0.f, 0.f, 0.f};
            f32x4 acc1 = {0.f, 0.f, 0.f, 0.f};
#pragma unroll
            for (int t9 = 0; t9 < 9; ++t9) {
                int dy = t9 / 3, dx = t9 - dy * 3;
#pragma unroll
                for (int kb = 0; kb < 2; ++kb) {
                    int g0 = (kb * 4 + lrow) * NP + (r0 + dy) * 18 + lcol + dx;
                    bf16x8 b0 = *(const bf16x8*)(xs + (size_t)g0 * 8);
                    acc0 = __builtin_amdgcn_mfma_f32_16x16x32_bf16(a[t9][kb], b0, acc0, 0, 0, 0);
                    bf16x8 b1 = *(const bf16x8*)(xs + ((size_t)g0 + 4 * 18) * 8);
                    acc1 = __builtin_amdgcn_mfma_f32_16x16x32_bf16(a[t9][kb], b1, acc1, 0, 0, 0);
                }
            }
            int yA = y0 + r0, yB = y0 + r0 + 4;
#pragma unroll
            for (int rg = 0; rg < 4; ++rg) {
                int co = co0 + lrow * 4 + rg;
                if (colok && co < C_out) {
                    float* oc = out + (((size_t)b * C_out + co) * H) * W + x0 + lcol;
                    if (yA < H) oc[(size_t)yA * W] = acc0[rg] * sc[rg] + sh[rg];
                    if (yB < H) oc[(size_t)yB * W] = acc1[rg] * sc[rg] + sh[rg];
                }
            }
        }
    }
}

// standalone conv3x3 (enc layers), grid (TX, TY, B*CSPLIT)
template<int COP, int CSPLIT, int MODE>
__global__ __launch_bounds__(256, 4)
void conv3x3_mfma(const float* __restrict__ x, const unsigned short* __restrict__ wt,
                  const float* __restrict__ p0, const float* __restrict__ p1,
                  const float* __restrict__ p2, const float* __restrict__ p3,
                  float* __restrict__ out, int H, int W, int C_out)
{
    __shared__ unsigned short xs[8 * 324 * 8];
    int TX = gridDim.x;
    int rem = (blockIdx.z) + gridDim.z * 0;
    // re-encode to flat rem for body: body expects rem = ((by*TX+bx)*4 + b)*CSPLIT + cs
    int cs = blockIdx.z % CSPLIT;
    int b  = blockIdx.z / CSPLIT;
    int flat = (((blockIdx.y * TX + blockIdx.x) * 4 + b) * CSPLIT) + cs;
    conv3x3_body<COP, CSPLIT, MODE>(flat, TX, xs, x, wt, p0, p1, p2, p3, out, H, W, C_out);
    (void)rem;
}

// fused fpn: all 3 output convs in one dispatch.
// level0 (96x160, CSPLIT2): blocks [0,480)   level1 (48x80, CSPLIT4): [480,720)
// level2 (24x40, CSPLIT4): [720,816)
__global__ __launch_bounds__(256, 4)
void fpn_multi(const float* __restrict__ l0, const unsigned short* __restrict__ wt0,
               const float* __restrict__ b0, float* __restrict__ o0,
               const float* __restrict__ l1, const unsigned short* __restrict__ wt1,
               const float* __restrict__ b1, float* __restrict__ o1,
               const float* __restrict__ l2, const unsigned short* __restrict__ wt2,
               const float* __restrict__ b2, float* __restrict__ o2)
{
    __shared__ unsigned short xs[8 * 324 * 8];
    int f = blockIdx.x;
    if (f < 480)
        conv3x3_body<64, 2, 0>(f, 10, xs, l0, wt0, b0, nullptr, nullptr, nullptr, o0, 96, 160, 64);
    else if (f < 720)
        conv3x3_body<64, 4, 0>(f - 480, 5, xs, l1, wt1, b1, nullptr, nullptr, nullptr, o1, 48, 80, 64);
    else
        conv3x3_body<64, 4, 0>(f - 720, 3, xs, l2, wt2, b2, nullptr, nullptr, nullptr, o2, 24, 40, 64);
}

// ---------------------------------------------------------------------------
// conv1x1 body (bf16 MFMA GEMM).  xs = 4*NPX*8 shorts of LDS.
// ---------------------------------------------------------------------------
template<int C_IN, int KSPLIT, int NPX, int MODE>
__device__ __forceinline__
void conv1x1_body(int f, unsigned short* xs,
                  const float* __restrict__ x, const unsigned short* __restrict__ wb,
                  const float* __restrict__ p0, const float* __restrict__ p1,
                  const float* __restrict__ p2, const float* __restrict__ p3,
                  float* __restrict__ out, int HW)
{
    constexpr int NT = NPX / 16;
    constexpr int KLEN = C_IN / KSPLIT;
    int nb = HW / NPX;
    int px0 = (f % nb) * NPX;
    int ks  = (f / nb) % KSPLIT;
    int b   = f / (nb * KSPLIT);

    int tid = threadIdx.x;
    int lane = tid & 63, wid = tid >> 6;
    int lrow = lane >> 4, lcol = lane & 15;
    const float* xb = x + (size_t)b * C_IN * HW + px0;

    f32x4 acc[NT];
#pragma unroll
    for (int nt = 0; nt < NT; ++nt) acc[nt] = (f32x4){0.f, 0.f, 0.f, 0.f};

    for (int cc = 0; cc < KLEN; cc += 32) {
        if (cc) __syncthreads();
        int cb = ks * KLEN + cc;
#pragma unroll
        for (int t = 0; t < NPX / 16; ++t) {
            int i = tid + t * 256;
            int px = i & (NPX - 1);
            int cp = i / NPX;
            float v0 = xb[(size_t)(cb + 2 * cp) * HW + px];
            float v1 = xb[(size_t)(cb + 2 * cp + 1) * HW + px];
            unsigned pk = ((unsigned)f2bf(v1) << 16) | (unsigned)f2bf(v0);
            ((unsigned*)xs)[((cp >> 2) * NPX + px) * 4 + (cp & 3)] = pk;
        }
        __syncthreads();

        bf16x8 a = *(const bf16x8*)(wb + (size_t)(wid * 16 + lcol) * C_IN + cb + lrow * 8);
#pragma unroll
        for (int nt = 0; nt < NT; ++nt) {
            bf16x8 bf = *(const bf16x8*)(xs + ((size_t)lrow * NPX + nt * 16 + lcol) * 8);
            acc[nt] = __builtin_amdgcn_mfma_f32_16x16x32_bf16(a, bf, acc[nt], 0, 0, 0);
        }
    }

    if (KSPLIT == 1) {
#pragma unroll
        for (int rg = 0; rg < 4; ++rg) {
            int co = wid * 16 + lrow * 4 + rg;
            float scale, shift;
            if (MODE == 0) { scale = 1.f; shift = p0[co]; }
            else {
                float inv = p0[co] * rsqrtf(p3[co] + BN_EPS);
                scale = inv; shift = p1[co] - p2[co] * inv;
            }
            float* op = out + ((size_t)(b * 64 + co)) * HW + px0;
#pragma unroll
            for (int nt = 0; nt < NT; ++nt) {
                float r = acc[nt][rg] * scale + shift;
                if (MODE == 1) r = fmaxf(r, 0.f);
                op[nt * 16 + lcol] = r;
            }
        }
    } else {
#pragma unroll
        for (int rg = 0; rg < 4; ++rg) {
            int co = wid * 16 + lrow * 4 + rg;
            float* op = out + (((size_t)(ks * 4 + b)) * 64 + co) * HW + px0;
#pragma unroll
            for (int nt = 0; nt < NT; ++nt)
                op[nt * 16 + lcol] = acc[nt][rg];
        }
    }
}

// standalone conv1x1 (comp layers), grid (HW/NPX, 1, B)
template<int C_IN, int KSPLIT, int NPX, int MODE>
__global__ __launch_bounds__(256, 4)
void conv1x1_mfma(const float* __restrict__ x, const unsigned short* __restrict__ wb,
                  const float* __restrict__ p0, const float* __restrict__ p1,
                  const float* __restrict__ p2, const float* __restrict__ p3,
                  float* __restrict__ out, int HW)
{
    __shared__ __align__(16) unsigned short xs[4 * NPX * 8];
    int nb = HW / NPX;
    int f = blockIdx.x + nb * (blockIdx.y + KSPLIT * blockIdx.z);
    conv1x1_body<C_IN, KSPLIT, NPX, MODE>(f, xs, x, wb, p0, p1, p2, p3, out, HW);
}

// fused lateral convs: lat0 [0,480), lat1->part [480,720), lat2->part [720,960)
__global__ __launch_bounds__(256, 4)
void lat_multi(const float* __restrict__ x0, const unsigned short* __restrict__ w0,
               const float* __restrict__ b0, float* __restrict__ lat0,
               const float* __restrict__ x1, const unsigned short* __restrict__ w1,
               float* __restrict__ part1,
               const float* __restrict__ x2, const unsigned short* __restrict__ w2,
               float* __restrict__ part2)
{
    __shared__ __align__(16) unsigned short xs[4 * 128 * 8];
    int f = blockIdx.x;
    if (f < 480)
        conv1x1_body<128, 1, 128, 0>(f, xs, x0, w0, b0, nullptr, nullptr, nullptr, lat0, 15360);
    else if (f < 720)
        conv1x1_body<256, 2, 128, 0>(f - 480, xs, x1, w1, nullptr, nullptr, nullptr, nullptr, part1, 3840);
    else
        conv1x1_body<512, 4, 64, 0>(f - 720, xs, x2, w2, nullptr, nullptr, nullptr, nullptr, part2, 960);
}

// ---------------------------------------------------------------------------
// fused K-split reduce + bias: lat1 blocks [0,960), lat2 blocks [960,1200)
// ---------------------------------------------------------------------------
template<int KSPLIT>
__device__ __forceinline__
void reduce_body(int f, const float* __restrict__ part, const float* __restrict__ bias,
                 float* __restrict__ out, int HW, int N4)
{
    int i = f * 256 + threadIdx.x;
    if (i >= N4) return;
    size_t base = (size_t)i * 4;
    int co = (int)((base / (size_t)HW) & 63);
    size_t stride = (size_t)HW << 8;
    float4 s = *(const float4*)(part + base);
#pragma unroll
    for (int ks = 1; ks < KSPLIT; ++ks) {
        float4 t = *(const float4*)(part + (size_t)ks * stride + base);
        s.x += t.x; s.y += t.y; s.z += t.z; s.w += t.w;
    }
    float bv = bias[co];
    s.x += bv; s.y += bv; s.z += bv; s.w += bv;
    *(float4*)(out + base) = s;
}

__global__ __launch_bounds__(256)
void reduce_multi(const float* __restrict__ part1, const float* __restrict__ b1,
                  float* __restrict__ lat1,
                  const float* __restrict__ part2, const float* __restrict__ b2,
                  float* __restrict__ lat2)
{
    int f = blockIdx.x;
    if (f < 960) reduce_body<2>(f, part1, b1, lat1, 3840, 245760);
    else         reduce_body<4>(f - 960, part2, b2, lat2, 960, 61440);
}

// ---------------------------------------------------------------------------
// CARAFE v4 (R12 version — channel-group split, known good)
// grid: (2w/16, 2h/16, B * CGS), block 256
// ---------------------------------------------------------------------------
template<int CGS>
__global__ __launch_bounds__(256, 4)
void carafe_kernel(const float* __restrict__ src, const float* __restrict__ logits,
                   float* __restrict__ dst, int h, int w)
{
    constexpr int SW = 12, NPX = 144;
    constexpr int CH = 64 / CGS;
    constexpr int CS = CH + 4;
    __shared__ float ls[NPX * CS];

    int tid = threadIdx.x;
    int x0 = blockIdx.x * 16, y0 = blockIdx.y * 16;
    int b  = blockIdx.z / CGS;
    int cs = blockIdx.z % CGS;
    int H = 2 * h, W = 2 * w;
    int xs0 = (x0 >> 1) - 2, ys0 = (y0 >> 1) - 2;
    size_t hw = (size_t)h * w;
    const float* sb = src + ((size_t)(b * 64 + cs * CH)) * hw;

    for (int i = tid; i < NPX * CH; i += 256) {
        int c = i / NPX, p = i - c * NPX;
        int yy = p / SW, xx = p - yy * SW;
        int sy = ys0 + yy, sx = xs0 + xx;
        float v = 0.f;
        if (sy >= 0 && sy < h && sx >= 0 && sx < w)
            v = sb[(size_t)c * hw + (size_t)sy * w + sx];
        ls[p * CS + c] = v;
    }
    __syncthreads();

    int lx = tid & 15, ty = tid >> 4;
    int x = x0 + lx, y = y0 + ty;
    int xw = x >> 1, yh = y >> 1;
    int par = (y & 1) * 2 + (x & 1);

    const float* lp = logits + ((size_t)(b * 100 + par) * h + yh) * w + xw;
    float l[25];
    float mx = -1e30f;
#pragma unroll
    for (int k = 0; k < 25; ++k) {
        l[k] = lp[(size_t)(4 * k) * hw];
        mx = fmaxf(mx, l[k]);
    }
    float s = 0.f;
#pragma unroll
    for (int k = 0; k < 25; ++k) {
        l[k] = __expf(l[k] - mx);
        s += l[k];
    }
    float invs = 1.f / s;
#pragma unroll
    for (int k = 0; k < 25; ++k) l[k] *= invs;

    int pb = (yh - ys0 - 2) * SW + (xw - xs0 - 2);

#pragma unroll 1
    for (int cg = 0; cg < CH / 16; ++cg) {
        float acc[16];
#pragma unroll
        for (int c = 0; c < 16; ++c) acc[c] = 0.f;
#pragma unroll
        for (int k = 0; k < 25; ++k) {
            int ti = k / 5, tj = k - ti * 5;
            const float* q = &ls[(pb + ti * SW + tj) * CS + cg * 16];
            float wk = l[k];
#pragma unroll
            for (int c = 0; c < 16; ++c)
                acc[c] = fmaf(wk, q[c], acc[c]);
        }
        float* dp = dst + (((size_t)(b * 64 + cs * CH + cg * 16)) * H + y) * W + x;
#pragma unroll
        for (int c = 0; c < 16; ++c)
            dp[(size_t)c * H * W] += acc[c];
    }
}

// ---------------------------------------------------------------------------
extern "C" void kernel_launch(void* const* d_in, const int* in_sizes, int n_in,
                              void* d_out, int out_size, void* d_ws, size_t ws_size,
                              hipStream_t stream)
{
    const float* x0      = (const float*)d_in[0];
    const float* lat0_w  = (const float*)d_in[1];
    const float* lat0_b  = (const float*)d_in[2];
    const float* fpn0_w  = (const float*)d_in[3];
    const float* fpn0_b  = (const float*)d_in[4];
    const float* x1      = (const float*)d_in[5];
    const float* lat1_w  = (const float*)d_in[6];
    const float* lat1_b  = (const float*)d_in[7];
    const float* fpn1_w  = (const float*)d_in[8];
    const float* fpn1_b  = (const float*)d_in[9];
    const float* x2      = (const float*)d_in[10];
    const float* lat2_w  = (const float*)d_in[11];
    const float* lat2_b  = (const float*)d_in[12];
    const float* fpn2_w  = (const float*)d_in[13];
    const float* fpn2_b  = (const float*)d_in[14];
    const float* u0_comp_w = (const float*)d_in[15];
    const float* u0_enc_w  = (const float*)d_in[16];
    const float* u0_comp_g  = (const float*)d_in[17];
    const float* u0_comp_bt = (const float*)d_in[18];
    const float* u0_comp_m  = (const float*)d_in[19];
    const float* u0_comp_v  = (const float*)d_in[20];
    const float* u0_enc_g   = (const float*)d_in[21];
    const float* u0_enc_bt  = (const float*)d_in[22];
    const float* u0_enc_m   = (const float*)d_in[23];
    const float* u0_enc_v   = (const float*)d_in[24];
    const float* u1_comp_w = (const float*)d_in[25];
    const float* u1_enc_w  = (const float*)d_in[26];
    const float* u1_comp_g  = (const float*)d_in[27];
    const float* u1_comp_bt = (const float*)d_in[28];
    const float* u1_comp_m  = (const float*)d_in[29];
    const float* u1_comp_v  = (const float*)d_in[30];
    const float* u1_enc_g   = (const float*)d_in[31];
    const float* u1_enc_bt  = (const float*)d_in[32];
    const float* u1_enc_m   = (const float*)d_in[33];
    const float* u1_enc_v   = (const float*)d_in[34];

    float* out = (float*)d_out;
    const size_t OUT0 = 4ull * 64 * 96 * 160;   // 3,932,160
    const size_t OUT1 = 4ull * 64 * 48 * 80;    //   983,040
    const size_t OUT2 = 4ull * 64 * 24 * 40;    //   245,760
    float* out0 = out;
    float* out1 = out + OUT0;
    float* out2 = out + OUT0 + OUT1;

    float* lat0 = (float*)d_ws;
    float* lat1 = lat0 + OUT0;
    float* lat2 = lat1 + OUT1;
    unsigned short* wtb = (unsigned short*)(lat2 + OUT2);   // 239,616 bf16
    unsigned short* wt_fpn0 = wtb;
    unsigned short* wt_fpn1 = wtb + 36864;
    unsigned short* wt_fpn2 = wtb + 73728;
    unsigned short* wt_enc0 = wtb + 110592;
    unsigned short* wt_enc1 = wtb + 175104;
    unsigned short* wb = wtb + 239616;                      // 65,536 bf16 (1x1)
    unsigned short* wb_lat0  = wb;
    unsigned short* wb_lat1  = wb + 8192;
    unsigned short* wb_lat2  = wb + 24576;
    unsigned short* wb_comp0 = wb + 57344;
    unsigned short* wb_comp1 = wb + 61440;
    // out0 region doubles as scratch (fpn_multi overwrites it LAST):
    float* part1 = out0;                 // lat1 partials: 2*983,040
    float* part2 = out0 + 2 * OUT1;      // lat2 partials: 4*245,760 -> ends 2,949,120
    float* comp  = out0;                 // comp logits (after reduces consume parts)
    float* enc   = out0 + OUT1;          // enc logits

    dim3 blk(256);

    // 0) weight prep
    prep_weights<<<dim3(252, 10), blk, 0, stream>>>(
        fpn0_w, fpn1_w, fpn2_w, u0_enc_w, u1_enc_w, wtb,
        lat0_w, lat1_w, lat2_w, u0_comp_w, u1_comp_w, wb);

    // 1) all three lateral 1x1 convs — ONE dispatch (960 blocks)
    lat_multi<<<dim3(960), blk, 0, stream>>>(
        x0, wb_lat0, lat0_b, lat0, x1, wb_lat1, part1, x2, wb_lat2, part2);

    // 2) both K-split reduces — ONE dispatch (1200 blocks)
    reduce_multi<<<dim3(1200), blk, 0, stream>>>(
        part1, lat1_b, lat1, part2, lat2_b, lat2);

    // 3) CARAFE u1: lat1 += carafe(lat2)
    conv1x1_mfma<64, 1, 32, 1><<<dim3(30, 1, 4), blk, 0, stream>>>(
        lat2, wb_comp1, u1_comp_g, u1_comp_bt, u1_comp_m, u1_comp_v, comp, 24 * 40);
    conv3x3_mfma<112, 7, 1><<<dim3(3, 2, 28), blk, 0, stream>>>(
        comp, wt_enc1, u1_enc_g, u1_enc_bt, u1_enc_m, u1_enc_v, enc, 24, 40, 100);
    carafe_kernel<2><<<dim3(5, 3, 8), blk, 0, stream>>>(lat2, enc, lat1, 24, 40);

    // 4) CARAFE u0: lat0 += carafe(lat1)
    conv1x1_mfma<64, 1, 128, 1><<<dim3(30, 1, 4), blk, 0, stream>>>(
        lat1, wb_comp0, u0_comp_g, u0_comp_bt, u0_comp_m, u0_comp_v, comp, 48 * 80);
    conv3x3_mfma<112, 7, 1><<<dim3(5, 3, 28), blk, 0, stream>>>(
        comp, wt_enc0, u0_enc_g, u0_enc_bt, u0_enc_m, u0_enc_v, enc, 48, 80, 100);
    carafe_kernel<2><<<dim3(10, 6, 8), blk, 0, stream>>>(lat1, enc, lat0, 48, 80);

    // 5) all three output 3x3 convs — ONE dispatch (816 blocks, heavy first)
    fpn_multi<<<dim3(816), blk, 0, stream>>>(
        lat0, wt_fpn0, fpn0_b, out0,
        lat1, wt_fpn1, fpn1_b, out1,
        lat2, wt_fpn2, fpn2_b, out2);
}

// Round 14
// 360.947 us; speedup vs baseline: 1.7029x; 1.0753x over previous
//
#include <hip/hip_runtime.h>

#define BN_EPS 1e-5f

typedef __attribute__((ext_vector_type(8))) short bf16x8;
typedef __attribute__((ext_vector_type(4))) float f32x4;

__device__ __forceinline__ unsigned short f2bf(float f) {
    unsigned u = __float_as_uint(f);
    return (unsigned short)((u + 0x7fffu + ((u >> 16) & 1u)) >> 16);   // RNE
}

// ---------------------------------------------------------------------------
// Weight prep (ONE launch): conv3x3 -> wt[tap][co][ci] bf16; 1x1 -> bf16 cast
// grid (252, 10), block 256
// ---------------------------------------------------------------------------
__global__ __launch_bounds__(256)
void prep_weights(const float* __restrict__ w0, const float* __restrict__ w1,
                  const float* __restrict__ w2, const float* __restrict__ w3,
                  const float* __restrict__ w4, unsigned short* __restrict__ dst,
                  const float* __restrict__ v0, const float* __restrict__ v1,
                  const float* __restrict__ v2, const float* __restrict__ v3,
                  const float* __restrict__ v4, unsigned short* __restrict__ dst1)
{
    int z = blockIdx.y;
    int i = blockIdx.x * 256 + threadIdx.x;
    if (z < 5) {
        const float* src; unsigned short* d; int C_out, COP;
        if (z < 3) {
            COP = 64; C_out = 64;
            src = (z == 0) ? w0 : (z == 1 ? w1 : w2);
            d = dst + z * 36864;
            if (i >= 36864) return;
        } else {
            COP = 112; C_out = 100;
            src = (z == 3) ? w3 : w4;
            d = dst + 110592 + (z - 3) * 64512;
            if (i >= 64512) return;
        }
        int tap = i / (COP * 64);
        int rem = i - tap * (COP * 64);
        int co = rem >> 6, ci = rem & 63;
        float v = (co < C_out) ? src[((size_t)co * 64 + ci) * 9 + tap] : 0.f;
        d[i] = f2bf(v);
    } else {
        int zz = z - 5;
        const float* s; int n; int off;
        if (zz == 0)      { s = v0; n = 8192;  off = 0; }
        else if (zz == 1) { s = v1; n = 16384; off = 8192; }
        else if (zz == 2) { s = v2; n = 32768; off = 24576; }
        else if (zz == 3) { s = v3; n = 4096;  off = 57344; }
        else              { s = v4; n = 4096;  off = 61440; }
        if (i >= n) return;
        dst1[off + i] = f2bf(s[i]);
    }
}

// ---------------------------------------------------------------------------
// conv3x3 body (bf16 MFMA 16x16x32, C_in=64, fp32 acc).  xs = 41472 B LDS.
// H, W, TX runtime so ONE instantiation serves all levels (R13: three
// instantiations in fpn_multi merged to VGPR=176, occupancy-capped).
// ---------------------------------------------------------------------------
template<int COP, int CSPLIT, int MODE>
__device__ __forceinline__
void conv3x3_body(int rem, int TX, unsigned short* xs,
                  const float* __restrict__ x, const unsigned short* __restrict__ wt,
                  const float* __restrict__ p0, const float* __restrict__ p1,
                  const float* __restrict__ p2, const float* __restrict__ p3,
                  float* __restrict__ out, int H, int W, int C_out)
{
    constexpr int NP = 324;
    constexpr int CT = COP / 16;
    constexpr int CPB = CT / CSPLIT;

    int cs = rem % CSPLIT;
    int b  = (rem / CSPLIT) & 3;
    int t  = rem / (CSPLIT * 4);
    int x0 = (t % TX) * 16, y0 = (t / TX) * 16;

    int tid  = threadIdx.x;
    int lane = tid & 63, wid = tid >> 6;
    int lrow = lane >> 4, lcol = lane & 15;
    int HWp = H * W;
    const float* xb = x + (size_t)b * 64 * HWp;

    unsigned int* wsl = (unsigned int*)xs;
    for (int p = tid; p < NP; p += 256) {
        int py = p / 18, px = p - py * 18;
        int gy = y0 + py - 1, gx = x0 + px - 1;
        bool ok = (gy >= 0) && (gy < H) && (gx >= 0) && (gx < W);
        const float* gp = xb + (size_t)gy * W + gx;
#pragma unroll 8
        for (int cp = 0; cp < 32; ++cp) {
            float v0 = 0.f, v1 = 0.f;
            if (ok) {
                v0 = gp[(size_t)(2 * cp) * HWp];
                v1 = gp[(size_t)(2 * cp + 1) * HWp];
            }
            unsigned pk = ((unsigned)f2bf(v1) << 16) | (unsigned)f2bf(v0);
            wsl[((cp >> 2) * NP + p) * 4 + (cp & 3)] = pk;
        }
    }
    __syncthreads();

    bool colok = (x0 + lcol) < W;

    for (int ct = cs * CPB; ct < (cs + 1) * CPB; ++ct) {
        int co0 = ct * 16;

        bf16x8 a[9][2];
        const unsigned short* wl = wt + ((size_t)co0 + lcol) * 64 + lrow * 8;
#pragma unroll
        for (int t9 = 0; t9 < 9; ++t9)
#pragma unroll
            for (int kb = 0; kb < 2; ++kb)
                a[t9][kb] = *(const bf16x8*)(wl + (size_t)t9 * COP * 64 + kb * 32);

        float sc[4], sh[4];
#pragma unroll
        for (int rg = 0; rg < 4; ++rg) {
            int co = co0 + lrow * 4 + rg;
            int cc = (co < C_out) ? co : 0;
            if (MODE == 0) { sc[rg] = 1.f; sh[rg] = p0[cc]; }
            else {
                float inv = p0[cc] * rsqrtf(p3[cc] + BN_EPS);
                sc[rg] = inv; sh[rg] = p1[cc] - p2[cc] * inv;
            }
        }

#pragma unroll
        for (int rr = 0; rr < 2; ++rr) {
            int r0 = wid + rr * 8;
            f32x4 acc0 = {0.f, 0.f, 0.f, 0.f};
            f32x4 acc1 = {0.f, 0.f, 0.f, 0.f};
#pragma unroll
            for (int t9 = 0; t9 < 9; ++t9) {
                int dy = t9 / 3, dx = t9 - dy * 3;
#pragma unroll
                for (int kb = 0; kb < 2; ++kb) {
                    int g0 = (kb * 4 + lrow) * NP + (r0 + dy) * 18 + lcol + dx;
                    bf16x8 b0 = *(const bf16x8*)(xs + (size_t)g0 * 8);
                    acc0 = __builtin_amdgcn_mfma_f32_16x16x32_bf16(a[t9][kb], b0, acc0, 0, 0, 0);
                    bf16x8 b1 = *(const bf16x8*)(xs + ((size_t)g0 + 4 * 18) * 8);
                    acc1 = __builtin_amdgcn_mfma_f32_16x16x32_bf16(a[t9][kb], b1, acc1, 0, 0, 0);
                }
            }
            int yA = y0 + r0, yB = y0 + r0 + 4;
#pragma unroll
            for (int rg = 0; rg < 4; ++rg) {
                int co = co0 + lrow * 4 + rg;
                if (colok && co < C_out) {
                    float* oc = out + (((size_t)b * C_out + co) * H) * W + x0 + lcol;
                    if (yA < H) oc[(size_t)yA * W] = acc0[rg] * sc[rg] + sh[rg];
                    if (yB < H) oc[(size_t)yB * W] = acc1[rg] * sc[rg] + sh[rg];
                }
            }
        }
    }
}

// standalone conv3x3 (enc layers), grid (TX, TY, B*CSPLIT)
template<int COP, int CSPLIT, int MODE>
__global__ __launch_bounds__(256, 4)
void conv3x3_mfma(const float* __restrict__ x, const unsigned short* __restrict__ wt,
                  const float* __restrict__ p0, const float* __restrict__ p1,
                  const float* __restrict__ p2, const float* __restrict__ p3,
                  float* __restrict__ out, int H, int W, int C_out)
{
    __shared__ unsigned short xs[8 * 324 * 8];
    int TX = gridDim.x;
    int cs = blockIdx.z % CSPLIT;
    int b  = blockIdx.z / CSPLIT;
    int flat = (((blockIdx.y * TX + blockIdx.x) * 4 + b) * CSPLIT) + cs;
    conv3x3_body<COP, CSPLIT, MODE>(flat, TX, xs, x, wt, p0, p1, p2, p3, out, H, W, C_out);
}

// fused fpn v2: SINGLE <64,4,0> instantiation; per-block only pointers+dims
// differ (wave-uniform select). level0: [0,960)  level1: [960,1200)
// level2: [1200,1296).  grid (1296)
__global__ __launch_bounds__(256, 4)
void fpn_multi(const float* __restrict__ l0, const unsigned short* __restrict__ wt0,
               const float* __restrict__ b0, float* __restrict__ o0,
               const float* __restrict__ l1, const unsigned short* __restrict__ wt1,
               const float* __restrict__ b1, float* __restrict__ o1,
               const float* __restrict__ l2, const unsigned short* __restrict__ wt2,
               const float* __restrict__ b2, float* __restrict__ o2)
{
    __shared__ unsigned short xs[8 * 324 * 8];
    int f = blockIdx.x;
    const float* x; const unsigned short* wt; const float* bias; float* o;
    int H, W, TX, rem;
    if (f < 960)       { x = l0; wt = wt0; bias = b0; o = o0; H = 96; W = 160; TX = 10; rem = f; }
    else if (f < 1200) { x = l1; wt = wt1; bias = b1; o = o1; H = 48; W = 80;  TX = 5;  rem = f - 960; }
    else               { x = l2; wt = wt2; bias = b2; o = o2; H = 24; W = 40;  TX = 3;  rem = f - 1200; }
    conv3x3_body<64, 4, 0>(rem, TX, xs, x, wt, bias, nullptr, nullptr, nullptr, o, H, W, 64);
}

// ---------------------------------------------------------------------------
// conv1x1 body (bf16 MFMA GEMM).  xs = 4*NPX*8 shorts of LDS.
// ---------------------------------------------------------------------------
template<int C_IN, int KSPLIT, int NPX, int MODE>
__device__ __forceinline__
void conv1x1_body(int f, unsigned short* xs,
                  const float* __restrict__ x, const unsigned short* __restrict__ wb,
                  const float* __restrict__ p0, const float* __restrict__ p1,
                  const float* __restrict__ p2, const float* __restrict__ p3,
                  float* __restrict__ out, int HW)
{
    constexpr int NT = NPX / 16;
    constexpr int KLEN = C_IN / KSPLIT;
    int nb = HW / NPX;
    int px0 = (f % nb) * NPX;
    int ks  = (f / nb) % KSPLIT;
    int b   = f / (nb * KSPLIT);

    int tid = threadIdx.x;
    int lane = tid & 63, wid = tid >> 6;
    int lrow = lane >> 4, lcol = lane & 15;
    const float* xb = x + (size_t)b * C_IN * HW + px0;

    f32x4 acc[NT];
#pragma unroll
    for (int nt = 0; nt < NT; ++nt) acc[nt] = (f32x4){0.f, 0.f, 0.f, 0.f};

    for (int cc = 0; cc < KLEN; cc += 32) {
        if (cc) __syncthreads();
        int cb = ks * KLEN + cc;
#pragma unroll
        for (int t = 0; t < NPX / 16; ++t) {
            int i = tid + t * 256;
            int px = i & (NPX - 1);
            int cp = i / NPX;
            float v0 = xb[(size_t)(cb + 2 * cp) * HW + px];
            float v1 = xb[(size_t)(cb + 2 * cp + 1) * HW + px];
            unsigned pk = ((unsigned)f2bf(v1) << 16) | (unsigned)f2bf(v0);
            ((unsigned*)xs)[((cp >> 2) * NPX + px) * 4 + (cp & 3)] = pk;
        }
        __syncthreads();

        bf16x8 a = *(const bf16x8*)(wb + (size_t)(wid * 16 + lcol) * C_IN + cb + lrow * 8);
#pragma unroll
        for (int nt = 0; nt < NT; ++nt) {
            bf16x8 bf = *(const bf16x8*)(xs + ((size_t)lrow * NPX + nt * 16 + lcol) * 8);
            acc[nt] = __builtin_amdgcn_mfma_f32_16x16x32_bf16(a, bf, acc[nt], 0, 0, 0);
        }
    }

    if (KSPLIT == 1) {
#pragma unroll
        for (int rg = 0; rg < 4; ++rg) {
            int co = wid * 16 + lrow * 4 + rg;
            float scale, shift;
            if (MODE == 0) { scale = 1.f; shift = p0[co]; }
            else {
                float inv = p0[co] * rsqrtf(p3[co] + BN_EPS);
                scale = inv; shift = p1[co] - p2[co] * inv;
            }
            float* op = out + ((size_t)(b * 64 + co)) * HW + px0;
#pragma unroll
            for (int nt = 0; nt < NT; ++nt) {
                float r = acc[nt][rg] * scale + shift;
                if (MODE == 1) r = fmaxf(r, 0.f);
                op[nt * 16 + lcol] = r;
            }
        }
    } else {
#pragma unroll
        for (int rg = 0; rg < 4; ++rg) {
            int co = wid * 16 + lrow * 4 + rg;
            float* op = out + (((size_t)(ks * 4 + b)) * 64 + co) * HW + px0;
#pragma unroll
            for (int nt = 0; nt < NT; ++nt)
                op[nt * 16 + lcol] = acc[nt][rg];
        }
    }
}

// standalone conv1x1 (comp layers), grid (HW/NPX, 1, B)
template<int C_IN, int KSPLIT, int NPX, int MODE>
__global__ __launch_bounds__(256, 4)
void conv1x1_mfma(const float* __restrict__ x, const unsigned short* __restrict__ wb,
                  const float* __restrict__ p0, const float* __restrict__ p1,
                  const float* __restrict__ p2, const float* __restrict__ p3,
                  float* __restrict__ out, int HW)
{
    __shared__ __align__(16) unsigned short xs[4 * NPX * 8];
    int nb = HW / NPX;
    int f = blockIdx.x + nb * (blockIdx.y + KSPLIT * blockIdx.z);
    conv1x1_body<C_IN, KSPLIT, NPX, MODE>(f, xs, x, wb, p0, p1, p2, p3, out, HW);
}

// fused lateral convs: lat0 [0,480), lat1->part [480,720), lat2->part [720,960)
__global__ __launch_bounds__(256, 4)
void lat_multi(const float* __restrict__ x0, const unsigned short* __restrict__ w0,
               const float* __restrict__ b0, float* __restrict__ lat0,
               const float* __restrict__ x1, const unsigned short* __restrict__ w1,
               float* __restrict__ part1,
               const float* __restrict__ x2, const unsigned short* __restrict__ w2,
               float* __restrict__ part2)
{
    __shared__ __align__(16) unsigned short xs[4 * 128 * 8];
    int f = blockIdx.x;
    if (f < 480)
        conv1x1_body<128, 1, 128, 0>(f, xs, x0, w0, b0, nullptr, nullptr, nullptr, lat0, 15360);
    else if (f < 720)
        conv1x1_body<256, 2, 128, 0>(f - 480, xs, x1, w1, nullptr, nullptr, nullptr, nullptr, part1, 3840);
    else
        conv1x1_body<512, 4, 64, 0>(f - 720, xs, x2, w2, nullptr, nullptr, nullptr, nullptr, part2, 960);
}

// ---------------------------------------------------------------------------
// fused K-split reduce + bias: lat1 blocks [0,960), lat2 blocks [960,1200)
// ---------------------------------------------------------------------------
template<int KSPLIT>
__device__ __forceinline__
void reduce_body(int f, const float* __restrict__ part, const float* __restrict__ bias,
                 float* __restrict__ out, int HW, int N4)
{
    int i = f * 256 + threadIdx.x;
    if (i >= N4) return;
    size_t base = (size_t)i * 4;
    int co = (int)((base / (size_t)HW) & 63);
    size_t stride = (size_t)HW << 8;
    float4 s = *(const float4*)(part + base);
#pragma unroll
    for (int ks = 1; ks < KSPLIT; ++ks) {
        float4 t = *(const float4*)(part + (size_t)ks * stride + base);
        s.x += t.x; s.y += t.y; s.z += t.z; s.w += t.w;
    }
    float bv = bias[co];
    s.x += bv; s.y += bv; s.z += bv; s.w += bv;
    *(float4*)(out + base) = s;
}

__global__ __launch_bounds__(256)
void reduce_multi(const float* __restrict__ part1, const float* __restrict__ b1,
                  float* __restrict__ lat1,
                  const float* __restrict__ part2, const float* __restrict__ b2,
                  float* __restrict__ lat2)
{
    int f = blockIdx.x;
    if (f < 960) reduce_body<2>(f, part1, b1, lat1, 3840, 245760);
    else         reduce_body<4>(f - 960, part2, b2, lat2, 960, 61440);
}

// ---------------------------------------------------------------------------
// CARAFE v4 (R12 version — channel-group split, known good)
// grid: (2w/16, 2h/16, B * CGS), block 256
// ---------------------------------------------------------------------------
template<int CGS>
__global__ __launch_bounds__(256, 4)
void carafe_kernel(const float* __restrict__ src, const float* __restrict__ logits,
                   float* __restrict__ dst, int h, int w)
{
    constexpr int SW = 12, NPX = 144;
    constexpr int CH = 64 / CGS;
    constexpr int CS = CH + 4;
    __shared__ float ls[NPX * CS];

    int tid = threadIdx.x;
    int x0 = blockIdx.x * 16, y0 = blockIdx.y * 16;
    int b  = blockIdx.z / CGS;
    int cs = blockIdx.z % CGS;
    int H = 2 * h, W = 2 * w;
    int xs0 = (x0 >> 1) - 2, ys0 = (y0 >> 1) - 2;
    size_t hw = (size_t)h * w;
    const float* sb = src + ((size_t)(b * 64 + cs * CH)) * hw;

    for (int i = tid; i < NPX * CH; i += 256) {
        int c = i / NPX, p = i - c * NPX;
        int yy = p / SW, xx = p - yy * SW;
        int sy = ys0 + yy, sx = xs0 + xx;
        float v = 0.f;
        if (sy >= 0 && sy < h && sx >= 0 && sx < w)
            v = sb[(size_t)c * hw + (size_t)sy * w + sx];
        ls[p * CS + c] = v;
    }
    __syncthreads();

    int lx = tid & 15, ty = tid >> 4;
    int x = x0 + lx, y = y0 + ty;
    int xw = x >> 1, yh = y >> 1;
    int par = (y & 1) * 2 + (x & 1);

    const float* lp = logits + ((size_t)(b * 100 + par) * h + yh) * w + xw;
    float l[25];
    float mx = -1e30f;
#pragma unroll
    for (int k = 0; k < 25; ++k) {
        l[k] = lp[(size_t)(4 * k) * hw];
        mx = fmaxf(mx, l[k]);
    }
    float s = 0.f;
#pragma unroll
    for (int k = 0; k < 25; ++k) {
        l[k] = __expf(l[k] - mx);
        s += l[k];
    }
    float invs = 1.f / s;
#pragma unroll
    for (int k = 0; k < 25; ++k) l[k] *= invs;

    int pb = (yh - ys0 - 2) * SW + (xw - xs0 - 2);

#pragma unroll 1
    for (int cg = 0; cg < CH / 16; ++cg) {
        float acc[16];
#pragma unroll
        for (int c = 0; c < 16; ++c) acc[c] = 0.f;
#pragma unroll
        for (int k = 0; k < 25; ++k) {
            int ti = k / 5, tj = k - ti * 5;
            const float* q = &ls[(pb + ti * SW + tj) * CS + cg * 16];
            float wk = l[k];
#pragma unroll
            for (int c = 0; c < 16; ++c)
                acc[c] = fmaf(wk, q[c], acc[c]);
        }
        float* dp = dst + (((size_t)(b * 64 + cs * CH + cg * 16)) * H + y) * W + x;
#pragma unroll
        for (int c = 0; c < 16; ++c)
            dp[(size_t)c * H * W] += acc[c];
    }
}

// ---------------------------------------------------------------------------
extern "C" void kernel_launch(void* const* d_in, const int* in_sizes, int n_in,
                              void* d_out, int out_size, void* d_ws, size_t ws_size,
                              hipStream_t stream)
{
    const float* x0      = (const float*)d_in[0];
    const float* lat0_w  = (const float*)d_in[1];
    const float* lat0_b  = (const float*)d_in[2];
    const float* fpn0_w  = (const float*)d_in[3];
    const float* fpn0_b  = (const float*)d_in[4];
    const float* x1      = (const float*)d_in[5];
    const float* lat1_w  = (const float*)d_in[6];
    const float* lat1_b  = (const float*)d_in[7];
    const float* fpn1_w  = (const float*)d_in[8];
    const float* fpn1_b  = (const float*)d_in[9];
    const float* x2      = (const float*)d_in[10];
    const float* lat2_w  = (const float*)d_in[11];
    const float* lat2_b  = (const float*)d_in[12];
    const float* fpn2_w  = (const float*)d_in[13];
    const float* fpn2_b  = (const float*)d_in[14];
    const float* u0_comp_w = (const float*)d_in[15];
    const float* u0_enc_w  = (const float*)d_in[16];
    const float* u0_comp_g  = (const float*)d_in[17];
    const float* u0_comp_bt = (const float*)d_in[18];
    const float* u0_comp_m  = (const float*)d_in[19];
    const float* u0_comp_v  = (const float*)d_in[20];
    const float* u0_enc_g   = (const float*)d_in[21];
    const float* u0_enc_bt  = (const float*)d_in[22];
    const float* u0_enc_m   = (const float*)d_in[23];
    const float* u0_enc_v   = (const float*)d_in[24];
    const float* u1_comp_w = (const float*)d_in[25];
    const float* u1_enc_w  = (const float*)d_in[26];
    const float* u1_comp_g  = (const float*)d_in[27];
    const float* u1_comp_bt = (const float*)d_in[28];
    const float* u1_comp_m  = (const float*)d_in[29];
    const float* u1_comp_v  = (const float*)d_in[30];
    const float* u1_enc_g   = (const float*)d_in[31];
    const float* u1_enc_bt  = (const float*)d_in[32];
    const float* u1_enc_m   = (const float*)d_in[33];
    const float* u1_enc_v   = (const float*)d_in[34];

    float* out = (float*)d_out;
    const size_t OUT0 = 4ull * 64 * 96 * 160;   // 3,932,160
    const size_t OUT1 = 4ull * 64 * 48 * 80;    //   983,040
    const size_t OUT2 = 4ull * 64 * 24 * 40;    //   245,760
    float* out0 = out;
    float* out1 = out + OUT0;
    float* out2 = out + OUT0 + OUT1;

    float* lat0 = (float*)d_ws;
    float* lat1 = lat0 + OUT0;
    float* lat2 = lat1 + OUT1;
    unsigned short* wtb = (unsigned short*)(lat2 + OUT2);   // 239,616 bf16
    unsigned short* wt_fpn0 = wtb;
    unsigned short* wt_fpn1 = wtb + 36864;
    unsigned short* wt_fpn2 = wtb + 73728;
    unsigned short* wt_enc0 = wtb + 110592;
    unsigned short* wt_enc1 = wtb + 175104;
    unsigned short* wb = wtb + 239616;                      // 65,536 bf16 (1x1)
    unsigned short* wb_lat0  = wb;
    unsigned short* wb_lat1  = wb + 8192;
    unsigned short* wb_lat2  = wb + 24576;
    unsigned short* wb_comp0 = wb + 57344;
    unsigned short* wb_comp1 = wb + 61440;
    // out0 region doubles as scratch (fpn_multi overwrites it LAST):
    float* part1 = out0;                 // lat1 partials: 2*983,040
    float* part2 = out0 + 2 * OUT1;      // lat2 partials: 4*245,760
    float* comp  = out0;                 // comp logits (after reduces consume parts)
    float* enc   = out0 + OUT1;          // enc logits

    dim3 blk(256);

    // 0) weight prep
    prep_weights<<<dim3(252, 10), blk, 0, stream>>>(
        fpn0_w, fpn1_w, fpn2_w, u0_enc_w, u1_enc_w, wtb,
        lat0_w, lat1_w, lat2_w, u0_comp_w, u1_comp_w, wb);

    // 1) all three lateral 1x1 convs — ONE dispatch (960 blocks)
    lat_multi<<<dim3(960), blk, 0, stream>>>(
        x0, wb_lat0, lat0_b, lat0, x1, wb_lat1, part1, x2, wb_lat2, part2);

    // 2) both K-split reduces — ONE dispatch (1200 blocks)
    reduce_multi<<<dim3(1200), blk, 0, stream>>>(
        part1, lat1_b, lat1, part2, lat2_b, lat2);

    // 3) CARAFE u1: lat1 += carafe(lat2)
    conv1x1_mfma<64, 1, 32, 1><<<dim3(30, 1, 4), blk, 0, stream>>>(
        lat2, wb_comp1, u1_comp_g, u1_comp_bt, u1_comp_m, u1_comp_v, comp, 24 * 40);
    conv3x3_mfma<112, 7, 1><<<dim3(3, 2, 28), blk, 0, stream>>>(
        comp, wt_enc1, u1_enc_g, u1_enc_bt, u1_enc_m, u1_enc_v, enc, 24, 40, 100);
    carafe_kernel<2><<<dim3(5, 3, 8), blk, 0, stream>>>(lat2, enc, lat1, 24, 40);

    // 4) CARAFE u0: lat0 += carafe(lat1)
    conv1x1_mfma<64, 1, 128, 1><<<dim3(30, 1, 4), blk, 0, stream>>>(
        lat1, wb_comp0, u0_comp_g, u0_comp_bt, u0_comp_m, u0_comp_v, comp, 48 * 80);
    conv3x3_mfma<112, 7, 1><<<dim3(5, 3, 28), blk, 0, stream>>>(
        comp, wt_enc0, u0_enc_g, u0_enc_bt, u0_enc_m, u0_enc_v, enc, 48, 80, 100);
    carafe_kernel<2><<<dim3(10, 6, 8), blk, 0, stream>>>(lat1, enc, lat0, 48, 80);

    // 5) all three output 3x3 convs — ONE dispatch, single instantiation
    fpn_multi<<<dim3(1296), blk, 0, stream>>>(
        lat0, wt_fpn0, fpn0_b, out0,
        lat1, wt_fpn1, fpn1_b, out1,
        lat2, wt_fpn2, fpn2_b, out2);
}